// Round 4
// baseline (580.523 us; speedup 1.0000x reference)
//
#include <hip/hip_runtime.h>

#define D 256
#define NC 64

using u16 = unsigned short;
using u32 = unsigned int;

typedef __attribute__((ext_vector_type(8))) short bfv8;   // 8 bf16 = 16 B
typedef __attribute__((ext_vector_type(4))) float f32x4;

__device__ __forceinline__ float bf2f(u32 u) {
  union { u32 i; float f; } v; v.i = u << 16; return v.f;
}
__device__ __forceinline__ u16 f2bf(float f) {
  union { float f; u32 i; } v; v.f = f;
  u32 x = v.i;
  return (u16)((x + 0x7FFFu + ((x >> 16) & 1u)) >> 16);  // RTNE
}
__device__ __forceinline__ u32 pk2(float a, float b) {
  return (u32)f2bf(a) | ((u32)f2bf(b) << 16);
}

__device__ __forceinline__ void gload_lds16(const void* src, void* dst) {
  __builtin_amdgcn_global_load_lds(
      (const __attribute__((address_space(1))) void*)src,
      (__attribute__((address_space(3))) void*)dst, 16, 0, 0);
}

#define PH_LDS 136192   // prep: A 64K + B 64K + nfpart 4K + bvs 1K
#define DIST_LDS 66560  // B dbuf 2x32K + red

// ---------------------------------------------------------------------------
// Blocked Gauss-Jordan inverse, NB=16, 1024 threads (16 waves).
// Wave w owns rows 16w..16w+15 (x[16][4]); step s: pivot wave = s.
// ---------------------------------------------------------------------------
__device__ void gj_body(const float* __restrict__ W, float* __restrict__ IW,
                        char* smem) {
  float (*Ml)[20]   = (float(*)[20])smem;            // 20480 B
  float (*Arow)[256] = (float(*)[256])(smem + 20480); // 16384 B
  float (*G)[256]    = (float(*)[256])(smem + 36864); // 16384 B
  float (*Pinv)[20]  = (float(*)[20])(smem + 53248);  // 1280 B
  const int t = threadIdx.x, w = t >> 6, l = t & 63;
  float x[16][4];
#pragma unroll
  for (int i = 0; i < 16; ++i) {
    float4 v = *(const float4*)(W + (size_t)(16 * w + i) * D + 4 * l);
    x[i][0] = v.x; x[i][1] = v.y; x[i][2] = v.z; x[i][3] = v.w;
  }
  for (int s = 0; s < 16; ++s) {
    const bool inC = ((l >> 2) == s);
    const int co = (l & 3) << 2;
    // 1) stage panel columns; pivot wave stages its 16 rows
    if (inC) {
#pragma unroll
      for (int i = 0; i < 16; ++i)
        *(float4*)&Ml[16 * w + i][co] =
            make_float4(x[i][0], x[i][1], x[i][2], x[i][3]);
    }
    if (w == s) {
#pragma unroll
      for (int q = 0; q < 16; ++q)
        *(float4*)&Arow[q][4 * l] =
            make_float4(x[q][0], x[q][1], x[q][2], x[q][3]);
    }
    __syncthreads();
    // 2) lanes 0..15 of wave 0: invert the 16x16 pivot block
    if (t < 16) {
      float p[16];
      {
        float4 r0 = *(const float4*)&Ml[16 * s + t][0];
        float4 r1 = *(const float4*)&Ml[16 * s + t][4];
        float4 r2 = *(const float4*)&Ml[16 * s + t][8];
        float4 r3 = *(const float4*)&Ml[16 * s + t][12];
        p[0] = r0.x; p[1] = r0.y; p[2] = r0.z; p[3] = r0.w;
        p[4] = r1.x; p[5] = r1.y; p[6] = r1.z; p[7] = r1.w;
        p[8] = r2.x; p[9] = r2.y; p[10] = r2.z; p[11] = r2.w;
        p[12] = r3.x; p[13] = r3.y; p[14] = r3.z; p[15] = r3.w;
      }
#pragma unroll
      for (int pp = 0; pp < 16; ++pp) {
        float u[16];
#pragma unroll
        for (int j = 0; j < 16; ++j)
          u[j] = __int_as_float(__builtin_amdgcn_readlane(__float_as_int(p[j]), pp));
        const float pv = u[pp];
        const float d = 1.0f / pv;
        if (t == pp) {
#pragma unroll
          for (int j = 0; j < 16; ++j) p[j] = u[j] * d;
          p[pp] = d;
        } else {
          const float md = p[pp] * d;
          u[pp] = pv + 1.0f;
#pragma unroll
          for (int j = 0; j < 16; ++j) p[j] = fmaf(-md, u[j], p[j]);
        }
      }
#pragma unroll
      for (int j = 0; j < 16; ++j) Pinv[t][j] = p[j];
    }
    __syncthreads();
    // 3) G row w = Pinv[w] * Arow  (C-cols hold I + Pinv)
    {
      float4 g = make_float4(0.f, 0.f, 0.f, 0.f);
#pragma unroll
      for (int q = 0; q < 16; ++q) {
        const float pv = Pinv[w][q];
        const float4 av = *(const float4*)&Arow[q][4 * l];
        g.x = fmaf(pv, av.x, g.x); g.y = fmaf(pv, av.y, g.y);
        g.z = fmaf(pv, av.z, g.z); g.w = fmaf(pv, av.w, g.w);
      }
      if (inC) {
        g.x = Pinv[w][co + 0] + (w == co + 0 ? 1.f : 0.f);
        g.y = Pinv[w][co + 1] + (w == co + 1 ? 1.f : 0.f);
        g.z = Pinv[w][co + 2] + (w == co + 2 ? 1.f : 0.f);
        g.w = Pinv[w][co + 3] + (w == co + 3 ? 1.f : 0.f);
      }
      *(float4*)&G[w][4 * l] = g;
    }
    __syncthreads();
    // 4) update / readback
    if (w == s) {  // pivot rows: readback
#pragma unroll
      for (int i = 0; i < 16; ++i) {
        if (inC) {
          x[i][0] = Pinv[i][co + 0]; x[i][1] = Pinv[i][co + 1];
          x[i][2] = Pinv[i][co + 2]; x[i][3] = Pinv[i][co + 3];
        } else {
          const float4 g = *(const float4*)&G[i][4 * l];
          x[i][0] = g.x; x[i][1] = g.y; x[i][2] = g.z; x[i][3] = g.w;
        }
      }
    } else {
#pragma unroll
      for (int hh = 0; hh < 4; ++hh) {
        float4 Gv[4];
#pragma unroll
        for (int q = 0; q < 4; ++q) Gv[q] = *(const float4*)&G[hh * 4 + q][4 * l];
#pragma unroll
        for (int i = 0; i < 16; ++i) {
          const float4 mm = *(const float4*)&Ml[16 * w + i][hh * 4];
          x[i][0] = fmaf(-mm.x, Gv[0].x, x[i][0]);
          x[i][1] = fmaf(-mm.x, Gv[0].y, x[i][1]);
          x[i][2] = fmaf(-mm.x, Gv[0].z, x[i][2]);
          x[i][3] = fmaf(-mm.x, Gv[0].w, x[i][3]);
          x[i][0] = fmaf(-mm.y, Gv[1].x, x[i][0]);
          x[i][1] = fmaf(-mm.y, Gv[1].y, x[i][1]);
          x[i][2] = fmaf(-mm.y, Gv[1].z, x[i][2]);
          x[i][3] = fmaf(-mm.y, Gv[1].w, x[i][3]);
          x[i][0] = fmaf(-mm.z, Gv[2].x, x[i][0]);
          x[i][1] = fmaf(-mm.z, Gv[2].y, x[i][1]);
          x[i][2] = fmaf(-mm.z, Gv[2].z, x[i][2]);
          x[i][3] = fmaf(-mm.z, Gv[2].w, x[i][3]);
          x[i][0] = fmaf(-mm.w, Gv[3].x, x[i][0]);
          x[i][1] = fmaf(-mm.w, Gv[3].y, x[i][1]);
          x[i][2] = fmaf(-mm.w, Gv[3].z, x[i][2]);
          x[i][3] = fmaf(-mm.w, Gv[3].w, x[i][3]);
        }
      }
    }
    __syncthreads();
  }
#pragma unroll
  for (int i = 0; i < 16; ++i)
    *(float4*)(IW + (size_t)(16 * w + i) * D + 4 * l) =
        make_float4(x[i][0], x[i][1], x[i][2], x[i][3]);
}

// ---------------------------------------------------------------------------
// prep body, 1024 threads: block = 128 rows x 128 cols (jh) x K256.
// Out = bf16(A) @ Brows^T + bias, class-major. Also: exact f32 input row
// norms (nrm) and rounded-output row-norm partials (nfp, per jh).
//   MODE 0: bias[col] = biasv[col]
//   MODE 1: bias[col] = -sum_k biasv[k]*bf16(Brows[col][k])  (folds the -b)
// ---------------------------------------------------------------------------
template <int MODE>
__device__ void prep_body(const float* __restrict__ Ain,
                          const u16* __restrict__ Brows,
                          const float* __restrict__ biasv,
                          u16* __restrict__ Out, float* __restrict__ nrm,
                          float* __restrict__ nfp, int bid, char* smem) {
  const int it = bid >> 1, jh = bid & 1;
  const int tx = threadIdx.x, ww = tx >> 6, l = tx & 63;
  const int wm2 = ww >> 3, wn8 = ww & 7, l4 = l >> 4, lm = l & 15;
  char* Ab = smem;
  char* Bb = smem + 65536;
  float* nfpart = (float*)(smem + 131072);  // [8][128]
  float* bvs = (float*)(smem + 135168);     // 256 f32
  // B staging (fragment order) via global_load_lds
#pragma unroll
  for (int u = 0; u < 4; ++u) {
    const int chunk = ww * 4 + u, ks = chunk >> 3, jf = chunk & 7;
    const u16* src = Brows + (size_t)(jh * 128 + jf * 16 + lm) * D + ks * 32 + l4 * 8;
    gload_lds16(src, Bb + chunk * 1024);
  }
  if (MODE == 1 && tx < 64) *(float4*)(bvs + tx * 4) = *(const float4*)(biasv + tx * 4);
  // A staging: f32 -> bf16 fragments + exact row norms
  {
    const int r = tx >> 3, sg = tx & 7;
    const float* arow = Ain + (size_t)(it * 128 + r) * D + sg * 32;
    float ss = 0.f;
#pragma unroll
    for (int g2 = 0; g2 < 4; ++g2) {
      float4 v0 = *(const float4*)(arow + g2 * 8);
      float4 v1 = *(const float4*)(arow + g2 * 8 + 4);
      ss = fmaf(v0.x, v0.x, fmaf(v0.y, v0.y, fmaf(v0.z, v0.z, fmaf(v0.w, v0.w, ss))));
      ss = fmaf(v1.x, v1.x, fmaf(v1.y, v1.y, fmaf(v1.z, v1.z, fmaf(v1.w, v1.w, ss))));
      uint4 w4;
      w4.x = pk2(v0.x, v0.y); w4.y = pk2(v0.z, v0.w);
      w4.z = pk2(v1.x, v1.y); w4.w = pk2(v1.z, v1.w);
      *(uint4*)(Ab + (sg * 8 + (r >> 4)) * 1024 + ((r & 15) + g2 * 16) * 16) = w4;
    }
    ss += __shfl_xor(ss, 1, 64);
    ss += __shfl_xor(ss, 2, 64);
    ss += __shfl_xor(ss, 4, 64);
    if (sg == 0) {
      const int g = it * 128 + r;
      nrm[((g & 63) << 10) | (g >> 6)] = ss;  // class-major (dup across jh, benign)
    }
  }
  __syncthreads();
  // MFMA: wave = 64 rows (wm2) x 16 cols (wn8)
  const bfv8* A8 = (const bfv8*)Ab;
  const bfv8* B8 = (const bfv8*)Bb;
  bfv8 bfr[8];
#pragma unroll
  for (int ks = 0; ks < 8; ++ks) bfr[ks] = B8[(ks * 8 + wn8) * 64 + l];
  f32x4 acc[4];
#pragma unroll
  for (int m = 0; m < 4; ++m) acc[m] = f32x4{0.f, 0.f, 0.f, 0.f};
#pragma unroll
  for (int ks = 0; ks < 8; ++ks) {
#pragma unroll
    for (int m = 0; m < 4; ++m) {
      bfv8 a = A8[(ks * 8 + wm2 * 4 + m) * 64 + l];
      acc[m] = __builtin_amdgcn_mfma_f32_16x16x32_bf16(a, bfr[ks], acc[m], 0, 0, 0);
    }
  }
  // bias
  float bias;
  if (MODE == 0) {
    bias = biasv[jh * 128 + wn8 * 16 + lm];
  } else {
    float pd = 0.f;
#pragma unroll
    for (int ks = 0; ks < 8; ++ks)
#pragma unroll
      for (int e = 0; e < 8; ++e)
        pd = fmaf(bvs[ks * 32 + l4 * 8 + e], bf2f((u16)bfr[ks][e]), pd);
    pd += __shfl_xor(pd, 16, 64);
    pd += __shfl_xor(pd, 32, 64);
    bias = -pd;
  }
  // epilogue: store bf16 + rounded-norm partials
  const int col = jh * 128 + wn8 * 16 + lm;
#pragma unroll
  for (int m = 0; m < 4; ++m)
#pragma unroll
    for (int rr = 0; rr < 4; ++rr) {
      const float v = acc[m][rr] + bias;
      const u16 hv = f2bf(v);
      const float vr = bf2f(hv);
      const int g = it * 128 + wm2 * 64 + m * 16 + l4 * 4 + rr;
      const size_t cm = ((size_t)(g & 63) << 10) | (g >> 6);
      Out[cm * D + col] = hv;
      float v2 = vr * vr;
      v2 += __shfl_xor(v2, 1, 64);
      v2 += __shfl_xor(v2, 2, 64);
      v2 += __shfl_xor(v2, 4, 64);
      v2 += __shfl_xor(v2, 8, 64);
      if (lm == 0) nfpart[wn8 * 128 + wm2 * 64 + m * 16 + l4 * 4 + rr] = v2;
    }
  __syncthreads();
  if (tx < 128) {
    float s = 0.f;
#pragma unroll
    for (int q = 0; q < 8; ++q) s += nfpart[q * 128 + tx];
    const int g = it * 128 + tx;
    nfp[((g & 63) << 10) | (g >> 6)] = s;
  }
}

// phase1: block 0 = gj inverse; blocks 1..1024 = prep<0> (F = p1@W^T + b)
__global__ __launch_bounds__(1024) void phase1_kernel(
    const float* __restrict__ p1, const float* __restrict__ W,
    const u16* __restrict__ Wb, const float* __restrict__ bv,
    u16* __restrict__ Fb, float* __restrict__ n1, float* __restrict__ nfp0,
    float* __restrict__ nfp1, float* __restrict__ IWa) {
  extern __shared__ char smem[];
  if (blockIdx.x == 0) {
    gj_body(W, IWa, smem);
  } else {
    const int bid = blockIdx.x - 1;
    prep_body<0>(p1, Wb, bv, Fb, n1, (bid & 1) ? nfp1 : nfp0, bid, smem);
  }
}

// phase3: prep<1> (Q = (p2-b)@IW^T via bias fold)
__global__ __launch_bounds__(1024) void phase3_kernel(
    const float* __restrict__ p2, const u16* __restrict__ IWb,
    const float* __restrict__ bv, u16* __restrict__ Qb,
    float* __restrict__ n2, float* __restrict__ nqp0, float* __restrict__ nqp1) {
  extern __shared__ char smem[];
  const int bid = blockIdx.x;
  prep_body<1>(p2, IWb, bv, Qb, n2, (bid & 1) ? nqp1 : nqp0, bid, smem);
}

// ---------------------------------------------------------------------------
// Newton-Schulz: R = 2I - W*X ; Y = X*R  (final Y stored as bf16)
// ---------------------------------------------------------------------------
__global__ __launch_bounds__(256) void nr_residual(const float* __restrict__ W,
                                                   const float* __restrict__ X,
                                                   float* __restrict__ R) {
  __shared__ float wrow[D];
  const int i = blockIdx.x, j = threadIdx.x;
  wrow[j] = W[i * D + j];
  __syncthreads();
  float acc = 0.f;
#pragma unroll 8
  for (int k = 0; k < D; ++k) acc = fmaf(wrow[k], X[k * D + j], acc);
  R[i * D + j] = (i == j ? 2.0f : 0.0f) - acc;
}

__global__ __launch_bounds__(256) void nr_mult(const float* __restrict__ X,
                                               const float* __restrict__ R,
                                               float* __restrict__ Y) {
  __shared__ float xrow[D];
  const int i = blockIdx.x, j = threadIdx.x;
  xrow[j] = X[i * D + j];
  __syncthreads();
  float acc = 0.f;
#pragma unroll 8
  for (int k = 0; k < D; ++k) acc = fmaf(xrow[k], R[k * D + j], acc);
  Y[i * D + j] = acc;
}

__global__ __launch_bounds__(256) void nr_mult_bf16(const float* __restrict__ X,
                                                    const float* __restrict__ R,
                                                    u16* __restrict__ Yb) {
  __shared__ float xrow[D];
  const int i = blockIdx.x, j = threadIdx.x;
  xrow[j] = X[i * D + j];
  __syncthreads();
  float acc = 0.f;
#pragma unroll 8
  for (int k = 0; k < D; ++k) acc = fmaf(xrow[k], R[k * D + j], acc);
  Yb[i * D + j] = f2bf(acc);
}

__global__ __launch_bounds__(256) void wconv(const float* __restrict__ W,
                                             u16* __restrict__ Wb) {
  const int i = blockIdx.x * 256 + threadIdx.x;
  Wb[i] = f2bf(W[i]);
}

// ---------------------------------------------------------------------------
// dist v2: 256 threads, A-fragments in registers (wave = 32 rows x full 128
// cols), B double-buffered in LDS (2x32KB) -> 2 blocks/CU.
// ---------------------------------------------------------------------------
__global__ __launch_bounds__(256, 2) void dist_kernel(
    const float* __restrict__ p1, const float* __restrict__ p2,
    const u16* __restrict__ Qb, const u16* __restrict__ Fb,
    const float* __restrict__ n1, const float* __restrict__ n2,
    const float* __restrict__ nqp0, const float* __restrict__ nqp1,
    const float* __restrict__ nfp0, const float* __restrict__ nfp1,
    float* __restrict__ partial) {
  extern __shared__ char smem[];
  const int bid = blockIdx.x;
  const int lb = (bid & 7) * 128 + (bid >> 3);   // XCD-chunked swizzle
  const int c = lb >> 4, dir = (lb >> 3) & 1, it = lb & 7;
  const float* Ain = dir ? p2 : p1;
  const u16* Bin = dir ? Fb : Qb;
  const float* nA = dir ? n2 : n1;
  const float* nB0 = dir ? nfp0 : nqp0;
  const float* nB1 = dir ? nfp1 : nqp1;
  const int tx = threadIdx.x, wid = tx >> 6, l = tx & 63;
  const int l4 = l >> 4, lm = l & 15;

  auto issue_b = [&](int half, int jt) {
    const size_t base = ((size_t)(c << 10) + jt * 128) * D;
#pragma unroll
    for (int jf = 0; jf < 8; ++jf) {
      const u16* src = Bin + base + (size_t)(jf * 16 + lm) * D
                       + half * 128 + wid * 32 + l4 * 8;
      gload_lds16(src, smem + half * 32768 + (wid * 8 + jf) * 1024);
    }
  };

  issue_b(0, 0);
  // A fragments -> registers (rows wid*32 + m*16 + lm)
  bfv8 afr[2][8];
  const float* abase = Ain + ((size_t)(it * 128 + wid * 32) * NC + c) * D;
#pragma unroll
  for (int m = 0; m < 2; ++m)
#pragma unroll
    for (int ks = 0; ks < 8; ++ks) {
      const float* ap = abase + (size_t)(m * 16 + lm) * (NC * D) + ks * 32 + l4 * 8;
      float4 v0 = *(const float4*)(ap);
      float4 v1 = *(const float4*)(ap + 4);
      union { bfv8 v; uint4 u; } cv;
      cv.u.x = pk2(v0.x, v0.y); cv.u.y = pk2(v0.z, v0.w);
      cv.u.z = pk2(v1.x, v1.y); cv.u.w = pk2(v1.z, v1.w);
      afr[m][ks] = cv.v;
    }
  float na[2][4];
#pragma unroll
  for (int m = 0; m < 2; ++m)
#pragma unroll
    for (int rr = 0; rr < 4; ++rr)
      na[m][rr] = nA[(c << 10) + it * 128 + wid * 32 + m * 16 + l4 * 4 + rr];
  float minv[2][4];
#pragma unroll
  for (int m = 0; m < 2; ++m)
#pragma unroll
    for (int rr = 0; rr < 4; ++rr) minv[m][rr] = 3.0e38f;
  __syncthreads();

  const bfv8* lds8 = (const bfv8*)smem;
  for (int jt = 0; jt < 8; ++jt) {
    f32x4 acc[2][8];
#pragma unroll
    for (int m = 0; m < 2; ++m)
#pragma unroll
      for (int n = 0; n < 8; ++n) acc[m][n] = f32x4{0.f, 0.f, 0.f, 0.f};
    float nbv[8];
#pragma unroll
    for (int n = 0; n < 8; ++n) {
      const int idx = (c << 10) + jt * 128 + n * 16 + lm;
      nbv[n] = nB0[idx] + nB1[idx];
    }
    issue_b(1, jt);
#pragma unroll
    for (int ks = 0; ks < 4; ++ks) {
      bfv8 bb[8];
#pragma unroll
      for (int n = 0; n < 8; ++n) bb[n] = lds8[(ks * 8 + n) * 64 + l];
#pragma unroll
      for (int m = 0; m < 2; ++m)
#pragma unroll
        for (int n = 0; n < 8; ++n)
          acc[m][n] = __builtin_amdgcn_mfma_f32_16x16x32_bf16(afr[m][ks], bb[n], acc[m][n], 0, 0, 0);
    }
    __syncthreads();
    if (jt < 7) issue_b(0, jt + 1);
#pragma unroll
    for (int ks = 4; ks < 8; ++ks) {
      bfv8 bb[8];
#pragma unroll
      for (int n = 0; n < 8; ++n) bb[n] = lds8[2048 + ((ks - 4) * 8 + n) * 64 + l];
#pragma unroll
      for (int m = 0; m < 2; ++m)
#pragma unroll
        for (int n = 0; n < 8; ++n)
          acc[m][n] = __builtin_amdgcn_mfma_f32_16x16x32_bf16(afr[m][ks], bb[n], acc[m][n], 0, 0, 0);
    }
#pragma unroll
    for (int m = 0; m < 2; ++m)
#pragma unroll
      for (int n = 0; n < 8; ++n)
#pragma unroll
        for (int rr = 0; rr < 4; ++rr) {
          const float dd = na[m][rr] + nbv[n] - 2.0f * acc[m][n][rr];
          minv[m][rr] = fminf(minv[m][rr], dd);
        }
    __syncthreads();
  }
  // reduce: each row owned by exactly one wave
  float* red = (float*)(smem + 65536);
#pragma unroll
  for (int m = 0; m < 2; ++m)
#pragma unroll
    for (int rr = 0; rr < 4; ++rr) {
      float mm = minv[m][rr];
      mm = fminf(mm, __shfl_xor(mm, 1, 64));
      mm = fminf(mm, __shfl_xor(mm, 2, 64));
      mm = fminf(mm, __shfl_xor(mm, 4, 64));
      mm = fminf(mm, __shfl_xor(mm, 8, 64));
      if (lm == 0) red[wid * 32 + m * 16 + l4 * 4 + rr] = mm;
    }
  __syncthreads();
  if (tx < 128) {
    float v = red[tx];
#pragma unroll
    for (int off = 32; off; off >>= 1) v += __shfl_xor(v, off, 64);
    if ((tx & 63) == 0) red[128 + (tx >> 6)] = v;
  }
  __syncthreads();
  if (tx == 0) partial[lb] = red[128] + red[129];
}

__global__ void finalize_kernel(const float* __restrict__ partial,
                                float* __restrict__ out) {
  const int tx = threadIdx.x;
  if (tx >= 128) return;
  const int dir = tx >> 6, c = tx & 63;
  float s = 0.f;
#pragma unroll
  for (int it = 0; it < 8; ++it) s += partial[(c << 4) | (dir << 3) | it];
  out[dir * 64 + c] = s * (1.0f / 1024.0f);
}

extern "C" void kernel_launch(void* const* d_in, const int* in_sizes, int n_in,
                              void* d_out, int out_size, void* d_ws, size_t ws_size,
                              hipStream_t stream) {
  const float* p1 = (const float*)d_in[0];
  const float* p2 = (const float*)d_in[1];
  const float* W  = (const float*)d_in[2];
  const float* bv = (const float*)d_in[3];
  float* out = (float*)d_out;
  char* ws = (char*)d_ws;
  float* n1   = (float*)(ws);                    // 256KB
  float* n2   = (float*)(ws + (256 << 10));      // 256KB
  float* nfp0 = (float*)(ws + (512 << 10));      // 256KB
  float* nfp1 = (float*)(ws + (768 << 10));      // 256KB
  float* nqp0 = (float*)(ws + (1024 << 10));     // 256KB (aliases Rt)
  float* nqp1 = (float*)(ws + (1280 << 10));     // 256KB (aliases IWc)
  float* Rt   = nqp0;   // dead before nqp0 written (phase3)
  float* IWc  = nqp1;   // dead before nqp1 written (phase3)
  float* partial = (float*)(ws + (1536 << 10));  // 4KB
  u16* Wb  = (u16*)(ws + (1544 << 10));          // 128KB
  u16* IWb = (u16*)(ws + (1672 << 10));          // 128KB
  u16* Fb  = (u16*)(ws + (1824 << 10));                   // 32MB
  u16* Qb  = (u16*)(ws + (1824 << 10) + (32u << 20));     // 32MB
  // IWa lives in the tail of Qb (dead before phase3 writes Qb)
  float* IWa = (float*)((char*)Qb + (32u << 20) - (256 << 10));

  hipFuncSetAttribute((const void*)phase1_kernel,
                      hipFuncAttributeMaxDynamicSharedMemorySize, PH_LDS);
  hipFuncSetAttribute((const void*)phase3_kernel,
                      hipFuncAttributeMaxDynamicSharedMemorySize, PH_LDS);
  hipFuncSetAttribute((const void*)dist_kernel,
                      hipFuncAttributeMaxDynamicSharedMemorySize, DIST_LDS);

  wconv<<<256, 256, 0, stream>>>(W, Wb);
  // gj inverse (block 0) runs concurrently with F-prep (blocks 1..1024)
  phase1_kernel<<<1025, 1024, PH_LDS, stream>>>(p1, W, Wb, bv, Fb, n1, nfp0, nfp1, IWa);
  nr_residual<<<256, 256, 0, stream>>>(W, IWa, Rt);
  nr_mult<<<256, 256, 0, stream>>>(IWa, Rt, IWc);
  nr_residual<<<256, 256, 0, stream>>>(W, IWc, Rt);
  nr_mult_bf16<<<256, 256, 0, stream>>>(IWc, Rt, IWb);
  phase3_kernel<<<1024, 1024, PH_LDS, stream>>>(p2, IWb, bv, Qb, n2, nqp0, nqp1);
  dist_kernel<<<1024, 256, DIST_LDS, stream>>>(p1, p2, Qb, Fb, n1, n2,
                                               nqp0, nqp1, nfp0, nfp1, partial);
  finalize_kernel<<<1, 128, 0, stream>>>(partial, out);
}

// Round 5
// 350.294 us; speedup vs baseline: 1.6572x; 1.6572x over previous
//
#include <hip/hip_runtime.h>

#define D 256
#define NC 64

using u16 = unsigned short;
using u32 = unsigned int;

typedef __attribute__((ext_vector_type(8))) short bfv8;   // 8 bf16 = 16 B
typedef __attribute__((ext_vector_type(4))) float f32x4;

__device__ __forceinline__ float bf2f(u32 u) {
  union { u32 i; float f; } v; v.i = u << 16; return v.f;
}
__device__ __forceinline__ u16 f2bf(float f) {
  union { float f; u32 i; } v; v.f = f;
  u32 x = v.i;
  return (u16)((x + 0x7FFFu + ((x >> 16) & 1u)) >> 16);  // RTNE
}
__device__ __forceinline__ u32 pk2(float a, float b) {
  return (u32)f2bf(a) | ((u32)f2bf(b) << 16);
}
__device__ __forceinline__ size_t cmrow(int g) {   // class-major row index
  return (size_t)(((g & 63) << 10) | (g >> 6));
}

__device__ __forceinline__ void gload_lds16(const void* src, void* dst) {
  __builtin_amdgcn_global_load_lds(
      (const __attribute__((address_space(1))) void*)src,
      (__attribute__((address_space(3))) void*)dst, 16, 0, 0);
}

#define PH_LDS 67584    // prep: A 64K + nfpart 2K  (gj uses 54.5K of it)
#define DIST_LDS 66560  // B dbuf 2x32K + red

// ---------------------------------------------------------------------------
// Blocked Gauss-Jordan inverse, NB=16, 512 threads (8 waves) — ROUND-3 BODY
// (measured 213 us). Wave w owns rows 32w..32w+31 (x[32][4] in VGPRs).
// ---------------------------------------------------------------------------
__device__ void gj_body(const float* __restrict__ W, float* __restrict__ IW,
                        char* smem) {
  float (*Ml)[20]    = (float(*)[20])smem;             // 256x20 = 20480 B
  float (*Arow)[256] = (float(*)[256])(smem + 20480);  // 16 KB
  float (*G)[256]    = (float(*)[256])(smem + 36864);  // 16 KB
  float (*Pinv)[20]  = (float(*)[20])(smem + 53248);   // 1280 B
  const int t = threadIdx.x, w = t >> 6, l = t & 63;
  float x[32][4];
#pragma unroll
  for (int i = 0; i < 32; ++i) {
    float4 v = *(const float4*)(W + (size_t)(32 * w + i) * D + 4 * l);
    x[i][0] = v.x; x[i][1] = v.y; x[i][2] = v.z; x[i][3] = v.w;
  }
  for (int s = 0; s < 16; ++s) {
    const int pw = s >> 1, ph = s & 1;
    const bool inC = ((l >> 2) == s);
    const int co = (l & 3) << 2;
    if (inC) {
#pragma unroll
      for (int i = 0; i < 32; ++i)
        *(float4*)&Ml[32 * w + i][co] =
            make_float4(x[i][0], x[i][1], x[i][2], x[i][3]);
    }
    if (w == pw) {
      if (ph == 0) {
#pragma unroll
        for (int q = 0; q < 16; ++q)
          *(float4*)&Arow[q][4 * l] =
              make_float4(x[q][0], x[q][1], x[q][2], x[q][3]);
      } else {
#pragma unroll
        for (int q = 0; q < 16; ++q)
          *(float4*)&Arow[q][4 * l] =
              make_float4(x[16 + q][0], x[16 + q][1], x[16 + q][2], x[16 + q][3]);
      }
    }
    __syncthreads();
    if (t < 16) {
      float p[16];
      {
        float4 r0 = *(const float4*)&Ml[16 * s + t][0];
        float4 r1 = *(const float4*)&Ml[16 * s + t][4];
        float4 r2 = *(const float4*)&Ml[16 * s + t][8];
        float4 r3 = *(const float4*)&Ml[16 * s + t][12];
        p[0] = r0.x; p[1] = r0.y; p[2] = r0.z; p[3] = r0.w;
        p[4] = r1.x; p[5] = r1.y; p[6] = r1.z; p[7] = r1.w;
        p[8] = r2.x; p[9] = r2.y; p[10] = r2.z; p[11] = r2.w;
        p[12] = r3.x; p[13] = r3.y; p[14] = r3.z; p[15] = r3.w;
      }
#pragma unroll
      for (int pp = 0; pp < 16; ++pp) {
        float u[16];
#pragma unroll
        for (int j = 0; j < 16; ++j)
          u[j] = __int_as_float(__builtin_amdgcn_readlane(__float_as_int(p[j]), pp));
        const float pv = u[pp];
        const float d = 1.0f / pv;
        if (t == pp) {
#pragma unroll
          for (int j = 0; j < 16; ++j) p[j] = u[j] * d;
          p[pp] = d;
        } else {
          const float md = p[pp] * d;
          u[pp] = pv + 1.0f;
#pragma unroll
          for (int j = 0; j < 16; ++j) p[j] = fmaf(-md, u[j], p[j]);
        }
      }
#pragma unroll
      for (int j = 0; j < 16; ++j) Pinv[t][j] = p[j];
    }
    __syncthreads();
#pragma unroll
    for (int h = 0; h < 2; ++h) {
      const int kk = 2 * w + h;
      float4 g = make_float4(0.f, 0.f, 0.f, 0.f);
#pragma unroll
      for (int q = 0; q < 16; ++q) {
        const float pv = Pinv[kk][q];
        const float4 av = *(const float4*)&Arow[q][4 * l];
        g.x = fmaf(pv, av.x, g.x); g.y = fmaf(pv, av.y, g.y);
        g.z = fmaf(pv, av.z, g.z); g.w = fmaf(pv, av.w, g.w);
      }
      if (inC) {
        g.x = Pinv[kk][co + 0] + (kk == co + 0 ? 1.f : 0.f);
        g.y = Pinv[kk][co + 1] + (kk == co + 1 ? 1.f : 0.f);
        g.z = Pinv[kk][co + 2] + (kk == co + 2 ? 1.f : 0.f);
        g.w = Pinv[kk][co + 3] + (kk == co + 3 ? 1.f : 0.f);
      }
      *(float4*)&G[kk][4 * l] = g;
    }
    __syncthreads();
#pragma unroll
    for (int hh = 0; hh < 2; ++hh) {
      float4 Gv[8];
#pragma unroll
      for (int k8 = 0; k8 < 8; ++k8)
        Gv[k8] = *(const float4*)&G[hh * 8 + k8][4 * l];
#pragma unroll
      for (int i = 0; i < 32; ++i) {
        const bool piv = (w == pw) && ((i >> 4) == ph);
        if (piv) {
          if (hh == 0) {
            const int q = i & 15;
            if (inC) {
              x[i][0] = Pinv[q][co + 0]; x[i][1] = Pinv[q][co + 1];
              x[i][2] = Pinv[q][co + 2]; x[i][3] = Pinv[q][co + 3];
            } else {
              const float4 g = *(const float4*)&G[q][4 * l];
              x[i][0] = g.x; x[i][1] = g.y; x[i][2] = g.z; x[i][3] = g.w;
            }
          }
        } else {
          const float4 m0 = *(const float4*)&Ml[32 * w + i][hh * 8];
          const float4 m1 = *(const float4*)&Ml[32 * w + i][hh * 8 + 4];
          const float mm[8] = {m0.x, m0.y, m0.z, m0.w, m1.x, m1.y, m1.z, m1.w};
#pragma unroll
          for (int k8 = 0; k8 < 8; ++k8) {
            x[i][0] = fmaf(-mm[k8], Gv[k8].x, x[i][0]);
            x[i][1] = fmaf(-mm[k8], Gv[k8].y, x[i][1]);
            x[i][2] = fmaf(-mm[k8], Gv[k8].z, x[i][2]);
            x[i][3] = fmaf(-mm[k8], Gv[k8].w, x[i][3]);
          }
        }
      }
    }
    __syncthreads();
  }
#pragma unroll
  for (int i = 0; i < 32; ++i)
    *(float4*)(IW + (size_t)(32 * w + i) * D + 4 * l) =
        make_float4(x[i][0], x[i][1], x[i][2], x[i][3]);
}

// ---------------------------------------------------------------------------
// prep body, 512 threads: block = 128 rows x 128 cols (jh) x K256.
// B fragments in REGISTERS (loaded from bf16 Brows global), A staged in LDS.
// Out = bf16(A) @ Brows^T + bias, class-major. Fused: exact input row norms
// (WRITE_NRM) + rounded-output row-norm partials (nfp, per jh half).
//   MODE 0: bias[col] = biasv[col]
//   MODE 1: bias[col] = -sum_k biasv[k]*bf16(Brows[col][k])   (folds the -b)
// Wave layout: 8 waves = 2 (mw: 64 rows) x 4 (nw: 32 cols).
// ---------------------------------------------------------------------------
template <int MODE, bool WRITE_NRM>
__device__ void prep_body(const float* __restrict__ Ain,
                          const u16* __restrict__ Brows,
                          const float* __restrict__ biasv,
                          u16* __restrict__ Out, float* __restrict__ nrm,
                          float* __restrict__ nfp, int bid, char* smem) {
  const int it = bid >> 1, jh = bid & 1;
  const int tx = threadIdx.x, ww = tx >> 6, l = tx & 63;
  const int mw = ww >> 2, nw = ww & 3, l4 = l >> 4, lm = l & 15;
  char* Ab = smem;
  float* nfpart = (float*)(smem + 65536);  // [4][128]

  // B fragments -> registers (16 x 16B loads from global, L2-hot)
  bfv8 bfr[2][8];
#pragma unroll
  for (int nf = 0; nf < 2; ++nf)
#pragma unroll
    for (int ks = 0; ks < 8; ++ks)
      bfr[nf][ks] = *(const bfv8*)(Brows +
          (size_t)(jh * 128 + nw * 32 + nf * 16 + lm) * D + ks * 32 + l4 * 8);

  // A staging: f32 -> bf16 fragments in LDS + exact row norms
  {
    const int r = tx >> 2, q = tx & 3;
    const float* arow = Ain + (size_t)(it * 128 + r) * D;
    float ss = 0.f;
#pragma unroll
    for (int kk = 0; kk < 2; ++kk) {
      const int ks = q * 2 + kk;
#pragma unroll
      for (int g2 = 0; g2 < 4; ++g2) {
        float4 v0 = *(const float4*)(arow + ks * 32 + g2 * 8);
        float4 v1 = *(const float4*)(arow + ks * 32 + g2 * 8 + 4);
        ss = fmaf(v0.x, v0.x, fmaf(v0.y, v0.y, fmaf(v0.z, v0.z, fmaf(v0.w, v0.w, ss))));
        ss = fmaf(v1.x, v1.x, fmaf(v1.y, v1.y, fmaf(v1.z, v1.z, fmaf(v1.w, v1.w, ss))));
        uint4 w4;
        w4.x = pk2(v0.x, v0.y); w4.y = pk2(v0.z, v0.w);
        w4.z = pk2(v1.x, v1.y); w4.w = pk2(v1.z, v1.w);
        *(uint4*)(Ab + ((ks * 8 + (r >> 4)) * 64 + g2 * 16 + (r & 15)) * 16) = w4;
      }
    }
    ss += __shfl_xor(ss, 1, 64);
    ss += __shfl_xor(ss, 2, 64);
    if (WRITE_NRM && q == 0) nrm[cmrow(it * 128 + r)] = ss;
  }
  __syncthreads();

  // MFMA: a-frag (LDS, shared) feeds both nf fragments
  const bfv8* A8 = (const bfv8*)Ab;
  f32x4 acc[4][2];
#pragma unroll
  for (int mf = 0; mf < 4; ++mf) {
    acc[mf][0] = f32x4{0.f, 0.f, 0.f, 0.f};
    acc[mf][1] = f32x4{0.f, 0.f, 0.f, 0.f};
  }
#pragma unroll
  for (int ks = 0; ks < 8; ++ks)
#pragma unroll
    for (int mf = 0; mf < 4; ++mf) {
      bfv8 a = A8[(ks * 8 + mw * 4 + mf) * 64 + l];
      acc[mf][0] = __builtin_amdgcn_mfma_f32_16x16x32_bf16(a, bfr[0][ks], acc[mf][0], 0, 0, 0);
      acc[mf][1] = __builtin_amdgcn_mfma_f32_16x16x32_bf16(a, bfr[1][ks], acc[mf][1], 0, 0, 0);
    }

  // bias per nf
  float bias[2];
  if (MODE == 0) {
#pragma unroll
    for (int nf = 0; nf < 2; ++nf)
      bias[nf] = biasv[jh * 128 + nw * 32 + nf * 16 + lm];
  } else {
#pragma unroll
    for (int nf = 0; nf < 2; ++nf) {
      float pd = 0.f;
#pragma unroll
      for (int ks = 0; ks < 8; ++ks) {
        float4 b0 = *(const float4*)(biasv + ks * 32 + l4 * 8);
        float4 b1 = *(const float4*)(biasv + ks * 32 + l4 * 8 + 4);
        pd = fmaf(b0.x, bf2f((u16)bfr[nf][ks][0]), pd);
        pd = fmaf(b0.y, bf2f((u16)bfr[nf][ks][1]), pd);
        pd = fmaf(b0.z, bf2f((u16)bfr[nf][ks][2]), pd);
        pd = fmaf(b0.w, bf2f((u16)bfr[nf][ks][3]), pd);
        pd = fmaf(b1.x, bf2f((u16)bfr[nf][ks][4]), pd);
        pd = fmaf(b1.y, bf2f((u16)bfr[nf][ks][5]), pd);
        pd = fmaf(b1.z, bf2f((u16)bfr[nf][ks][6]), pd);
        pd = fmaf(b1.w, bf2f((u16)bfr[nf][ks][7]), pd);
      }
      pd += __shfl_xor(pd, 16, 64);
      pd += __shfl_xor(pd, 32, 64);
      bias[nf] = -pd;
    }
  }

  // epilogue: bf16 store (class-major) + rounded row-norm partials
#pragma unroll
  for (int mf = 0; mf < 4; ++mf)
#pragma unroll
    for (int rr = 0; rr < 4; ++rr) {
      const int g = it * 128 + mw * 64 + mf * 16 + l4 * 4 + rr;
      const size_t orow = cmrow(g) * D;
      float v2 = 0.f;
#pragma unroll
      for (int nf = 0; nf < 2; ++nf) {
        const float v = acc[mf][nf][rr] + bias[nf];
        const u16 hv = f2bf(v);
        Out[orow + jh * 128 + nw * 32 + nf * 16 + lm] = hv;
        const float vr = bf2f(hv);
        v2 = fmaf(vr, vr, v2);
      }
      v2 += __shfl_xor(v2, 1, 64);
      v2 += __shfl_xor(v2, 2, 64);
      v2 += __shfl_xor(v2, 4, 64);
      v2 += __shfl_xor(v2, 8, 64);
      if (lm == 0) nfpart[nw * 128 + mw * 64 + mf * 16 + l4 * 4 + rr] = v2;
    }
  __syncthreads();
  if (tx < 128) {
    float s = nfpart[tx] + nfpart[128 + tx] + nfpart[256 + tx] + nfpart[384 + tx];
    nfp[cmrow(it * 128 + tx)] = s;
  }
}

// n2 norms role: 64 blocks x 512 thr, 1024 rows each, class-major write
__device__ void norms_role(const float* __restrict__ p2, float* __restrict__ n2,
                           int idx) {
  const int tx = threadIdx.x, q = tx & 3;
#pragma unroll
  for (int rep = 0; rep < 8; ++rep) {
    const int g = idx * 1024 + rep * 128 + (tx >> 2);
    const float* row = p2 + (size_t)g * D + q * 64;
    float ss = 0.f;
#pragma unroll
    for (int g2 = 0; g2 < 16; ++g2) {
      float4 v = *(const float4*)(row + g2 * 4);
      ss = fmaf(v.x, v.x, fmaf(v.y, v.y, fmaf(v.z, v.z, fmaf(v.w, v.w, ss))));
    }
    ss += __shfl_xor(ss, 1, 64);
    ss += __shfl_xor(ss, 2, 64);
    if (q == 0) n2[cmrow(g)] = ss;
  }
}

// phase1: block 0 = gj inverse; 1..1024 = prep<0> (F); 1025..1088 = n2 norms
__global__ __launch_bounds__(512) void phase1_kernel(
    const float* __restrict__ p1, const float* __restrict__ p2,
    const float* __restrict__ W, const u16* __restrict__ Wb,
    const float* __restrict__ bv, u16* __restrict__ Fb,
    float* __restrict__ n1, float* __restrict__ n2,
    float* __restrict__ nfp0, float* __restrict__ nfp1,
    float* __restrict__ IWa) {
  extern __shared__ char smem[];
  const int b = blockIdx.x;
  if (b == 0) {
    gj_body(W, IWa, smem);
  } else if (b <= 1024) {
    const int bid = b - 1;
    prep_body<0, true>(p1, Wb, bv, Fb, n1, (bid & 1) ? nfp1 : nfp0, bid, smem);
  } else {
    norms_role(p2, n2, b - 1025);
  }
}

// phase3: prep<1> (Q = (p2-b)@IW^T via bias fold)
__global__ __launch_bounds__(512, 4) void phase3_kernel(
    const float* __restrict__ p2, const u16* __restrict__ IWb,
    const float* __restrict__ bv, u16* __restrict__ Qb,
    float* __restrict__ nqp0, float* __restrict__ nqp1) {
  extern __shared__ char smem[];
  const int bid = blockIdx.x;
  prep_body<1, false>(p2, IWb, bv, Qb, nullptr,
                      (bid & 1) ? nqp1 : nqp0, bid, smem);
}

// ---------------------------------------------------------------------------
// Newton-Schulz (one iteration): R = 2I - W*X ; Y = X*R -> bf16
// ---------------------------------------------------------------------------
__global__ __launch_bounds__(256) void nr_residual(const float* __restrict__ W,
                                                   const float* __restrict__ X,
                                                   float* __restrict__ R) {
  __shared__ float wrow[D];
  const int i = blockIdx.x, j = threadIdx.x;
  wrow[j] = W[i * D + j];
  __syncthreads();
  float acc = 0.f;
#pragma unroll 8
  for (int k = 0; k < D; ++k) acc = fmaf(wrow[k], X[k * D + j], acc);
  R[i * D + j] = (i == j ? 2.0f : 0.0f) - acc;
}

__global__ __launch_bounds__(256) void nr_mult_bf16(const float* __restrict__ X,
                                                    const float* __restrict__ R,
                                                    u16* __restrict__ Yb) {
  __shared__ float xrow[D];
  const int i = blockIdx.x, j = threadIdx.x;
  xrow[j] = X[i * D + j];
  __syncthreads();
  float acc = 0.f;
#pragma unroll 8
  for (int k = 0; k < D; ++k) acc = fmaf(xrow[k], R[k * D + j], acc);
  Yb[i * D + j] = f2bf(acc);
}

__global__ __launch_bounds__(256) void wconv(const float* __restrict__ W,
                                             u16* __restrict__ Wb) {
  const int i = blockIdx.x * 256 + threadIdx.x;
  Wb[i] = f2bf(W[i]);
}

// ---------------------------------------------------------------------------
// dist v2 (round-3/4 proven): 256 thr, A-fragments in registers (wave = 32
// rows x full 128 cols), B double-buffered in LDS (2x32KB) -> 2 blocks/CU.
// ---------------------------------------------------------------------------
__global__ __launch_bounds__(256, 2) void dist_kernel(
    const float* __restrict__ p1, const float* __restrict__ p2,
    const u16* __restrict__ Qb, const u16* __restrict__ Fb,
    const float* __restrict__ n1, const float* __restrict__ n2,
    const float* __restrict__ nqp0, const float* __restrict__ nqp1,
    const float* __restrict__ nfp0, const float* __restrict__ nfp1,
    float* __restrict__ partial) {
  extern __shared__ char smem[];
  const int bid = blockIdx.x;
  const int lb = (bid & 7) * 128 + (bid >> 3);   // XCD-chunked swizzle
  const int c = lb >> 4, dir = (lb >> 3) & 1, it = lb & 7;
  const float* Ain = dir ? p2 : p1;
  const u16* Bin = dir ? Fb : Qb;
  const float* nA = dir ? n2 : n1;
  const float* nB0 = dir ? nfp0 : nqp0;
  const float* nB1 = dir ? nfp1 : nqp1;
  const int tx = threadIdx.x, wid = tx >> 6, l = tx & 63;
  const int l4 = l >> 4, lm = l & 15;

  auto issue_b = [&](int half, int jt) {
    const size_t base = ((size_t)(c << 10) + jt * 128) * D;
#pragma unroll
    for (int jf = 0; jf < 8; ++jf) {
      const u16* src = Bin + base + (size_t)(jf * 16 + lm) * D
                       + half * 128 + wid * 32 + l4 * 8;
      gload_lds16(src, smem + half * 32768 + (wid * 8 + jf) * 1024);
    }
  };

  issue_b(0, 0);
  bfv8 afr[2][8];
  const float* abase = Ain + ((size_t)(it * 128 + wid * 32) * NC + c) * D;
#pragma unroll
  for (int m = 0; m < 2; ++m)
#pragma unroll
    for (int ks = 0; ks < 8; ++ks) {
      const float* ap = abase + (size_t)(m * 16 + lm) * (NC * D) + ks * 32 + l4 * 8;
      float4 v0 = *(const float4*)(ap);
      float4 v1 = *(const float4*)(ap + 4);
      union { bfv8 v; uint4 u; } cv;
      cv.u.x = pk2(v0.x, v0.y); cv.u.y = pk2(v0.z, v0.w);
      cv.u.z = pk2(v1.x, v1.y); cv.u.w = pk2(v1.z, v1.w);
      afr[m][ks] = cv.v;
    }
  float na[2][4];
#pragma unroll
  for (int m = 0; m < 2; ++m)
#pragma unroll
    for (int rr = 0; rr < 4; ++rr)
      na[m][rr] = nA[(c << 10) + it * 128 + wid * 32 + m * 16 + l4 * 4 + rr];
  float minv[2][4];
#pragma unroll
  for (int m = 0; m < 2; ++m)
#pragma unroll
    for (int rr = 0; rr < 4; ++rr) minv[m][rr] = 3.0e38f;
  __syncthreads();

  const bfv8* lds8 = (const bfv8*)smem;
  for (int jt = 0; jt < 8; ++jt) {
    f32x4 acc[2][8];
#pragma unroll
    for (int m = 0; m < 2; ++m)
#pragma unroll
      for (int n = 0; n < 8; ++n) acc[m][n] = f32x4{0.f, 0.f, 0.f, 0.f};
    float nbv[8];
#pragma unroll
    for (int n = 0; n < 8; ++n) {
      const int idx = (c << 10) + jt * 128 + n * 16 + lm;
      nbv[n] = nB0[idx] + nB1[idx];
    }
    issue_b(1, jt);
#pragma unroll
    for (int ks = 0; ks < 4; ++ks) {
      bfv8 bb[8];
#pragma unroll
      for (int n = 0; n < 8; ++n) bb[n] = lds8[(ks * 8 + n) * 64 + l];
#pragma unroll
      for (int m = 0; m < 2; ++m)
#pragma unroll
        for (int n = 0; n < 8; ++n)
          acc[m][n] = __builtin_amdgcn_mfma_f32_16x16x32_bf16(afr[m][ks], bb[n], acc[m][n], 0, 0, 0);
    }
    __syncthreads();
    if (jt < 7) issue_b(0, jt + 1);
#pragma unroll
    for (int ks = 4; ks < 8; ++ks) {
      bfv8 bb[8];
#pragma unroll
      for (int n = 0; n < 8; ++n) bb[n] = lds8[2048 + ((ks - 4) * 8 + n) * 64 + l];
#pragma unroll
      for (int m = 0; m < 2; ++m)
#pragma unroll
        for (int n = 0; n < 8; ++n)
          acc[m][n] = __builtin_amdgcn_mfma_f32_16x16x32_bf16(afr[m][ks], bb[n], acc[m][n], 0, 0, 0);
    }
#pragma unroll
    for (int m = 0; m < 2; ++m)
#pragma unroll
      for (int n = 0; n < 8; ++n)
#pragma unroll
        for (int rr = 0; rr < 4; ++rr) {
          const float dd = na[m][rr] + nbv[n] - 2.0f * acc[m][n][rr];
          minv[m][rr] = fminf(minv[m][rr], dd);
        }
    __syncthreads();
  }
  float* red = (float*)(smem + 65536);
#pragma unroll
  for (int m = 0; m < 2; ++m)
#pragma unroll
    for (int rr = 0; rr < 4; ++rr) {
      float mm = minv[m][rr];
      mm = fminf(mm, __shfl_xor(mm, 1, 64));
      mm = fminf(mm, __shfl_xor(mm, 2, 64));
      mm = fminf(mm, __shfl_xor(mm, 4, 64));
      mm = fminf(mm, __shfl_xor(mm, 8, 64));
      if (lm == 0) red[wid * 32 + m * 16 + l4 * 4 + rr] = mm;
    }
  __syncthreads();
  if (tx < 128) {
    float v = red[tx];
#pragma unroll
    for (int off = 32; off; off >>= 1) v += __shfl_xor(v, off, 64);
    if ((tx & 63) == 0) red[128 + (tx >> 6)] = v;
  }
  __syncthreads();
  if (tx == 0) partial[lb] = red[128] + red[129];
}

__global__ void finalize_kernel(const float* __restrict__ partial,
                                float* __restrict__ out) {
  const int tx = threadIdx.x;
  if (tx >= 128) return;
  const int dir = tx >> 6, c = tx & 63;
  float s = 0.f;
#pragma unroll
  for (int it = 0; it < 8; ++it) s += partial[(c << 4) | (dir << 3) | it];
  out[dir * 64 + c] = s * (1.0f / 1024.0f);
}

extern "C" void kernel_launch(void* const* d_in, const int* in_sizes, int n_in,
                              void* d_out, int out_size, void* d_ws, size_t ws_size,
                              hipStream_t stream) {
  const float* p1 = (const float*)d_in[0];
  const float* p2 = (const float*)d_in[1];
  const float* W  = (const float*)d_in[2];
  const float* bv = (const float*)d_in[3];
  float* out = (float*)d_out;
  char* ws = (char*)d_ws;
  float* n1   = (float*)(ws);                    // 256KB
  float* n2   = (float*)(ws + (256 << 10));      // 256KB
  float* nfp0 = (float*)(ws + (512 << 10));      // 256KB
  float* nfp1 = (float*)(ws + (768 << 10));      // 256KB
  float* nqp0 = (float*)(ws + (1024 << 10));     // 256KB
  float* nqp1 = (float*)(ws + (1280 << 10));     // 256KB
  float* partial = (float*)(ws + (1536 << 10));  // 4KB
  u16* Wb  = (u16*)(ws + (1544 << 10));          // 128KB
  u16* IWb = (u16*)(ws + (1672 << 10));          // 128KB
  float* IWa = (float*)(ws + (1800 << 10));      // 256KB
  float* Rt  = (float*)(ws + (2056 << 10));      // 256KB
  u16* Fb  = (u16*)(ws + (2560 << 10));                   // 32MB
  u16* Qb  = (u16*)(ws + (2560 << 10) + (32u << 20));     // 32MB

  hipFuncSetAttribute((const void*)phase1_kernel,
                      hipFuncAttributeMaxDynamicSharedMemorySize, PH_LDS);
  hipFuncSetAttribute((const void*)phase3_kernel,
                      hipFuncAttributeMaxDynamicSharedMemorySize, PH_LDS);
  hipFuncSetAttribute((const void*)dist_kernel,
                      hipFuncAttributeMaxDynamicSharedMemorySize, DIST_LDS);

  wconv<<<256, 256, 0, stream>>>(W, Wb);
  // gj (block 0) runs concurrently with F-prep (1..1024) and n2 norms
  phase1_kernel<<<1089, 512, PH_LDS, stream>>>(p1, p2, W, Wb, bv, Fb,
                                               n1, n2, nfp0, nfp1, IWa);
  // one Newton-Schulz refinement, bf16 output
  nr_residual<<<256, 256, 0, stream>>>(W, IWa, Rt);
  nr_mult_bf16<<<256, 256, 0, stream>>>(IWa, Rt, IWb);
  phase3_kernel<<<1024, 512, PH_LDS, stream>>>(p2, IWb, bv, Qb, nqp0, nqp1);
  dist_kernel<<<1024, 256, DIST_LDS, stream>>>(p1, p2, Qb, Fb, n1, n2,
                                               nqp0, nqp1, nfp0, nfp1, partial);
  finalize_kernel<<<1, 128, 0, stream>>>(partial, out);
}

// Round 6
// 339.483 us; speedup vs baseline: 1.7100x; 1.0318x over previous
//
#include <hip/hip_runtime.h>

#define D 256
#define NC 64

using u16 = unsigned short;
using u32 = unsigned int;

typedef __attribute__((ext_vector_type(8))) short bfv8;   // 8 bf16 = 16 B
typedef __attribute__((ext_vector_type(4))) float f32x4;

__device__ __forceinline__ float bf2f(u32 u) {
  union { u32 i; float f; } v; v.i = u << 16; return v.f;
}
__device__ __forceinline__ u16 f2bf(float f) {
  union { float f; u32 i; } v; v.f = f;
  u32 x = v.i;
  return (u16)((x + 0x7FFFu + ((x >> 16) & 1u)) >> 16);  // RTNE
}
__device__ __forceinline__ u32 pk2(float a, float b) {
  return (u32)f2bf(a) | ((u32)f2bf(b) << 16);
}
__device__ __forceinline__ size_t cmrow(int g) {   // class-major row index
  return (size_t)(((g & 63) << 10) | (g >> 6));
}

__device__ __forceinline__ void gload_lds16(const void* src, void* dst) {
  __builtin_amdgcn_global_load_lds(
      (const __attribute__((address_space(1))) void*)src,
      (__attribute__((address_space(3))) void*)dst, 16, 0, 0);
}

#define PH_LDS 70912    // gj: Ml 20480 + Arow 16384 + G 16384 + Gfrag 16384 + Pinv 1280
#define DIST_LDS 66560  // B dbuf 2x32K + red

// ---------------------------------------------------------------------------
// Blocked Gauss-Jordan inverse, NB=16, 512 threads (8 waves), MFMA update.
// State: MFMA C-fragment layout. Wave w owns rows 32w..32w+31 as f32x4
// x[rt][ct] (rt: 16-row half, ct: 16-col tile); element (i,j) of a tile:
// lane = j + 16*(i>>2), reg = i&3.
// Per step: stage panel (f32, LDS) -> serial 16x16 Pinv (proven code) ->
// G = Pinv*Arow in f32 + bf16 hi/lo fragment-ordered copy -> update
// x += (-M)*G via 2 MFMAs/tile: A=[-Mhi,-Mlo] x B1=[Ghi,Glo], B2=[Glo,Ghi].
// ---------------------------------------------------------------------------
__device__ void gj_body(const float* __restrict__ W, float* __restrict__ IW,
                        char* smem) {
  float (*Ml)[20]    = (float(*)[20])smem;                 // 20480 B (f32 panel)
  float (*Arow)[256] = (float(*)[256])(smem + 20480);      // 16384 B
  float (*G)[256]    = (float(*)[256])(smem + 36864);      // 16384 B
  u16*  Gfrag        = (u16*)(smem + 53248);               // [16][64][8] bf16 = 16384 B
  float (*Pinv)[20]  = (float(*)[20])(smem + 69632);       // 1280 B
  const int t = threadIdx.x, w = t >> 6, l = t & 63;
  const int lj = l & 15, lh = l >> 4;
  const int r0 = 32 * w;

  f32x4 x[2][16];
#pragma unroll
  for (int rt = 0; rt < 2; ++rt)
#pragma unroll
    for (int ct = 0; ct < 16; ++ct)
#pragma unroll
      for (int reg = 0; reg < 4; ++reg)
        x[rt][ct][reg] = W[(size_t)(r0 + 16 * rt + 4 * lh + reg) * D + 16 * ct + lj];

  for (int s = 0; s < 16; ++s) {
    const int pw = s >> 1, ph = s & 1;
    // -------- Phase A: stage panel col-tile (all waves) + pivot rows --------
#pragma unroll
    for (int rt = 0; rt < 2; ++rt)
#pragma unroll
      for (int ct = 0; ct < 16; ++ct)
        if (ct == s)
#pragma unroll
          for (int reg = 0; reg < 4; ++reg)
            Ml[r0 + 16 * rt + 4 * lh + reg][lj] = x[rt][ct][reg];
    if (w == pw) {
#pragma unroll
      for (int rt = 0; rt < 2; ++rt)
        if (rt == ph)
#pragma unroll
          for (int ct = 0; ct < 16; ++ct)
#pragma unroll
            for (int reg = 0; reg < 4; ++reg)
              Arow[4 * lh + reg][16 * ct + lj] = x[rt][ct][reg];
    }
    __syncthreads();
    // -------- Phase B: serial 16x16 pivot-block inverse (proven code) ------
    if (t < 16) {
      float p[16];
      {
        float4 rr0 = *(const float4*)&Ml[16 * s + t][0];
        float4 rr1 = *(const float4*)&Ml[16 * s + t][4];
        float4 rr2 = *(const float4*)&Ml[16 * s + t][8];
        float4 rr3 = *(const float4*)&Ml[16 * s + t][12];
        p[0] = rr0.x; p[1] = rr0.y; p[2] = rr0.z; p[3] = rr0.w;
        p[4] = rr1.x; p[5] = rr1.y; p[6] = rr1.z; p[7] = rr1.w;
        p[8] = rr2.x; p[9] = rr2.y; p[10] = rr2.z; p[11] = rr2.w;
        p[12] = rr3.x; p[13] = rr3.y; p[14] = rr3.z; p[15] = rr3.w;
      }
#pragma unroll
      for (int pp = 0; pp < 16; ++pp) {
        float u[16];
#pragma unroll
        for (int j = 0; j < 16; ++j)
          u[j] = __int_as_float(__builtin_amdgcn_readlane(__float_as_int(p[j]), pp));
        const float pv = u[pp];
        const float d = 1.0f / pv;
        if (t == pp) {
#pragma unroll
          for (int j = 0; j < 16; ++j) p[j] = u[j] * d;
          p[pp] = d;
        } else {
          const float md = p[pp] * d;
          u[pp] = pv + 1.0f;
#pragma unroll
          for (int j = 0; j < 16; ++j) p[j] = fmaf(-md, u[j], p[j]);
        }
      }
#pragma unroll
      for (int j = 0; j < 16; ++j) Pinv[t][j] = p[j];
    }
    __syncthreads();
    // -------- Phase C: G rows 2w,2w+1 (f32) + bf16 frag-ordered copy -------
    {
      const bool inC = ((l >> 2) == s);
      const int co = (l & 3) << 2;
      const int gct = l >> 2;          // col-tile of this lane's 4 cols
#pragma unroll
      for (int h = 0; h < 2; ++h) {
        const int kk = 2 * w + h;
        float4 g = make_float4(0.f, 0.f, 0.f, 0.f);
#pragma unroll
        for (int q = 0; q < 16; ++q) {
          const float pv = Pinv[kk][q];
          const float4 av = *(const float4*)&Arow[q][4 * l];
          g.x = fmaf(pv, av.x, g.x); g.y = fmaf(pv, av.y, g.y);
          g.z = fmaf(pv, av.z, g.z); g.w = fmaf(pv, av.w, g.w);
        }
        if (inC) {
          g.x = Pinv[kk][co + 0] + (kk == co + 0 ? 1.f : 0.f);
          g.y = Pinv[kk][co + 1] + (kk == co + 1 ? 1.f : 0.f);
          g.z = Pinv[kk][co + 2] + (kk == co + 2 ? 1.f : 0.f);
          g.w = Pinv[kk][co + 3] + (kk == co + 3 ? 1.f : 0.f);
        }
        *(float4*)&G[kk][4 * l] = g;
        const int e0 = kk & 7;
        const int lbase = 16 * (kk >> 3);
        const float gv[4] = {g.x, g.y, g.z, g.w};
#pragma unroll
        for (int cc = 0; cc < 4; ++cc) {
          const int cl = 4 * (l & 3) + cc;   // col within tile
          const u16 hi = f2bf(gv[cc]);
          const u16 lo = f2bf(gv[cc] - bf2f(hi));
          Gfrag[(gct * 64 + lbase + cl) * 8 + e0] = hi;
          Gfrag[(gct * 64 + 32 + lbase + cl) * 8 + e0] = lo;
        }
      }
    }
    __syncthreads();
    // -------- Phase D: MFMA update / pivot-tile readback --------------------
    bfv8 afr[2];
#pragma unroll
    for (int rt = 0; rt < 2; ++rt) {
      const int row = r0 + 16 * rt + lj;
      float4 f0 = *(const float4*)&Ml[row][8 * (lh & 1)];
      float4 f1 = *(const float4*)&Ml[row][8 * (lh & 1) + 4];
      const float fv[8] = {f0.x, f0.y, f0.z, f0.w, f1.x, f1.y, f1.z, f1.w};
      union { bfv8 v; u16 e[8]; } A;
      if (lh < 2) {
#pragma unroll
        for (int e = 0; e < 8; ++e) A.e[e] = f2bf(-fv[e]);
      } else {
#pragma unroll
        for (int e = 0; e < 8; ++e) {
          const float hi = bf2f(f2bf(fv[e]));
          A.e[e] = f2bf(-(fv[e] - hi));
        }
      }
      afr[rt] = A.v;
    }
#pragma unroll
    for (int rt = 0; rt < 2; ++rt) {
      const bool skip = (w == pw) && (rt == ph);
      if (!skip) {
#pragma unroll
        for (int ct = 0; ct < 16; ++ct) {
          bfv8 b1 = *(const bfv8*)&Gfrag[(ct * 64 + l) * 8];
          bfv8 b2 = *(const bfv8*)&Gfrag[(ct * 64 + (l ^ 32)) * 8];
          x[rt][ct] = __builtin_amdgcn_mfma_f32_16x16x32_bf16(afr[rt], b1, x[rt][ct], 0, 0, 0);
          x[rt][ct] = __builtin_amdgcn_mfma_f32_16x16x32_bf16(afr[rt], b2, x[rt][ct], 0, 0, 0);
        }
      }
    }
    if (w == pw) {
#pragma unroll
      for (int rt = 0; rt < 2; ++rt)
        if (rt == ph)
#pragma unroll
          for (int ct = 0; ct < 16; ++ct) {
            if (ct == s) {
#pragma unroll
              for (int reg = 0; reg < 4; ++reg)
                x[rt][ct][reg] = Pinv[4 * lh + reg][lj];
            } else {
#pragma unroll
              for (int reg = 0; reg < 4; ++reg)
                x[rt][ct][reg] = G[4 * lh + reg][16 * ct + lj];
            }
          }
    }
    __syncthreads();
  }
#pragma unroll
  for (int rt = 0; rt < 2; ++rt)
#pragma unroll
    for (int ct = 0; ct < 16; ++ct)
#pragma unroll
      for (int reg = 0; reg < 4; ++reg)
        IW[(size_t)(r0 + 16 * rt + 4 * lh + reg) * D + 16 * ct + lj] = x[rt][ct][reg];
}

// ---------------------------------------------------------------------------
// prep body, 512 threads (round-5 proven): block = 128 rows x 128 cols (jh).
// B fragments in registers, A staged in LDS. Fused input norms + rounded
// output-norm partials. MODE 1 folds -b via bias = -b . bf16(Brows[col]).
// ---------------------------------------------------------------------------
template <int MODE, bool WRITE_NRM>
__device__ void prep_body(const float* __restrict__ Ain,
                          const u16* __restrict__ Brows,
                          const float* __restrict__ biasv,
                          u16* __restrict__ Out, float* __restrict__ nrm,
                          float* __restrict__ nfp, int bid, char* smem) {
  const int it = bid >> 1, jh = bid & 1;
  const int tx = threadIdx.x, ww = tx >> 6, l = tx & 63;
  const int mw = ww >> 2, nw = ww & 3, l4 = l >> 4, lm = l & 15;
  char* Ab = smem;
  float* nfpart = (float*)(smem + 65536);  // [4][128]

  bfv8 bfr[2][8];
#pragma unroll
  for (int nf = 0; nf < 2; ++nf)
#pragma unroll
    for (int ks = 0; ks < 8; ++ks)
      bfr[nf][ks] = *(const bfv8*)(Brows +
          (size_t)(jh * 128 + nw * 32 + nf * 16 + lm) * D + ks * 32 + l4 * 8);

  {
    const int r = tx >> 2, q = tx & 3;
    const float* arow = Ain + (size_t)(it * 128 + r) * D;
    float ss = 0.f;
#pragma unroll
    for (int kk = 0; kk < 2; ++kk) {
      const int ks = q * 2 + kk;
#pragma unroll
      for (int g2 = 0; g2 < 4; ++g2) {
        float4 v0 = *(const float4*)(arow + ks * 32 + g2 * 8);
        float4 v1 = *(const float4*)(arow + ks * 32 + g2 * 8 + 4);
        ss = fmaf(v0.x, v0.x, fmaf(v0.y, v0.y, fmaf(v0.z, v0.z, fmaf(v0.w, v0.w, ss))));
        ss = fmaf(v1.x, v1.x, fmaf(v1.y, v1.y, fmaf(v1.z, v1.z, fmaf(v1.w, v1.w, ss))));
        uint4 w4;
        w4.x = pk2(v0.x, v0.y); w4.y = pk2(v0.z, v0.w);
        w4.z = pk2(v1.x, v1.y); w4.w = pk2(v1.z, v1.w);
        *(uint4*)(Ab + ((ks * 8 + (r >> 4)) * 64 + g2 * 16 + (r & 15)) * 16) = w4;
      }
    }
    ss += __shfl_xor(ss, 1, 64);
    ss += __shfl_xor(ss, 2, 64);
    if (WRITE_NRM && q == 0) nrm[cmrow(it * 128 + r)] = ss;
  }
  __syncthreads();

  const bfv8* A8 = (const bfv8*)Ab;
  f32x4 acc[4][2];
#pragma unroll
  for (int mf = 0; mf < 4; ++mf) {
    acc[mf][0] = f32x4{0.f, 0.f, 0.f, 0.f};
    acc[mf][1] = f32x4{0.f, 0.f, 0.f, 0.f};
  }
#pragma unroll
  for (int ks = 0; ks < 8; ++ks)
#pragma unroll
    for (int mf = 0; mf < 4; ++mf) {
      bfv8 a = A8[(ks * 8 + mw * 4 + mf) * 64 + l];
      acc[mf][0] = __builtin_amdgcn_mfma_f32_16x16x32_bf16(a, bfr[0][ks], acc[mf][0], 0, 0, 0);
      acc[mf][1] = __builtin_amdgcn_mfma_f32_16x16x32_bf16(a, bfr[1][ks], acc[mf][1], 0, 0, 0);
    }

  float bias[2];
  if (MODE == 0) {
#pragma unroll
    for (int nf = 0; nf < 2; ++nf)
      bias[nf] = biasv[jh * 128 + nw * 32 + nf * 16 + lm];
  } else {
#pragma unroll
    for (int nf = 0; nf < 2; ++nf) {
      float pd = 0.f;
#pragma unroll
      for (int ks = 0; ks < 8; ++ks) {
        float4 b0 = *(const float4*)(biasv + ks * 32 + l4 * 8);
        float4 b1 = *(const float4*)(biasv + ks * 32 + l4 * 8 + 4);
        pd = fmaf(b0.x, bf2f((u16)bfr[nf][ks][0]), pd);
        pd = fmaf(b0.y, bf2f((u16)bfr[nf][ks][1]), pd);
        pd = fmaf(b0.z, bf2f((u16)bfr[nf][ks][2]), pd);
        pd = fmaf(b0.w, bf2f((u16)bfr[nf][ks][3]), pd);
        pd = fmaf(b1.x, bf2f((u16)bfr[nf][ks][4]), pd);
        pd = fmaf(b1.y, bf2f((u16)bfr[nf][ks][5]), pd);
        pd = fmaf(b1.z, bf2f((u16)bfr[nf][ks][6]), pd);
        pd = fmaf(b1.w, bf2f((u16)bfr[nf][ks][7]), pd);
      }
      pd += __shfl_xor(pd, 16, 64);
      pd += __shfl_xor(pd, 32, 64);
      bias[nf] = -pd;
    }
  }

#pragma unroll
  for (int mf = 0; mf < 4; ++mf)
#pragma unroll
    for (int rr = 0; rr < 4; ++rr) {
      const int g = it * 128 + mw * 64 + mf * 16 + l4 * 4 + rr;
      const size_t orow = cmrow(g) * D;
      float v2 = 0.f;
#pragma unroll
      for (int nf = 0; nf < 2; ++nf) {
        const float v = acc[mf][nf][rr] + bias[nf];
        const u16 hv = f2bf(v);
        Out[orow + jh * 128 + nw * 32 + nf * 16 + lm] = hv;
        const float vr = bf2f(hv);
        v2 = fmaf(vr, vr, v2);
      }
      v2 += __shfl_xor(v2, 1, 64);
      v2 += __shfl_xor(v2, 2, 64);
      v2 += __shfl_xor(v2, 4, 64);
      v2 += __shfl_xor(v2, 8, 64);
      if (lm == 0) nfpart[nw * 128 + mw * 64 + mf * 16 + l4 * 4 + rr] = v2;
    }
  __syncthreads();
  if (tx < 128) {
    float s = nfpart[tx] + nfpart[128 + tx] + nfpart[256 + tx] + nfpart[384 + tx];
    nfp[cmrow(it * 128 + tx)] = s;
  }
}

// n2 norms role: 64 blocks x 512 thr, 1024 rows each, class-major write
__device__ void norms_role(const float* __restrict__ p2, float* __restrict__ n2,
                           int idx) {
  const int tx = threadIdx.x, q = tx & 3;
#pragma unroll
  for (int rep = 0; rep < 8; ++rep) {
    const int g = idx * 1024 + rep * 128 + (tx >> 2);
    const float* row = p2 + (size_t)g * D + q * 64;
    float ss = 0.f;
#pragma unroll
    for (int g2 = 0; g2 < 16; ++g2) {
      float4 v = *(const float4*)(row + g2 * 4);
      ss = fmaf(v.x, v.x, fmaf(v.y, v.y, fmaf(v.z, v.z, fmaf(v.w, v.w, ss))));
    }
    ss += __shfl_xor(ss, 1, 64);
    ss += __shfl_xor(ss, 2, 64);
    if (q == 0) n2[cmrow(g)] = ss;
  }
}

// phase1: block 0 = gj inverse; 1..1024 = prep<0> (F); 1025..1088 = n2 norms
__global__ __launch_bounds__(512) void phase1_kernel(
    const float* __restrict__ p1, const float* __restrict__ p2,
    const float* __restrict__ W, const u16* __restrict__ Wb,
    const float* __restrict__ bv, u16* __restrict__ Fb,
    float* __restrict__ n1, float* __restrict__ n2,
    float* __restrict__ nfp0, float* __restrict__ nfp1,
    float* __restrict__ IWa) {
  extern __shared__ char smem[];
  const int b = blockIdx.x;
  if (b == 0) {
    gj_body(W, IWa, smem);
  } else if (b <= 1024) {
    const int bid = b - 1;
    prep_body<0, true>(p1, Wb, bv, Fb, n1, (bid & 1) ? nfp1 : nfp0, bid, smem);
  } else {
    norms_role(p2, n2, b - 1025);
  }
}

// phase3: prep<1> (Q = (p2-b)@IW^T via bias fold)
__global__ __launch_bounds__(512, 4) void phase3_kernel(
    const float* __restrict__ p2, const u16* __restrict__ IWb,
    const float* __restrict__ bv, u16* __restrict__ Qb,
    float* __restrict__ nqp0, float* __restrict__ nqp1) {
  extern __shared__ char smem[];
  const int bid = blockIdx.x;
  prep_body<1, false>(p2, IWb, bv, Qb, nullptr,
                      (bid & 1) ? nqp1 : nqp0, bid, smem);
}

// ---------------------------------------------------------------------------
// Newton-Schulz (one iteration): R = 2I - W*X ; Y = X*R -> bf16
// ---------------------------------------------------------------------------
__global__ __launch_bounds__(256) void nr_residual(const float* __restrict__ W,
                                                   const float* __restrict__ X,
                                                   float* __restrict__ R) {
  __shared__ float wrow[D];
  const int i = blockIdx.x, j = threadIdx.x;
  wrow[j] = W[i * D + j];
  __syncthreads();
  float acc = 0.f;
#pragma unroll 8
  for (int k = 0; k < D; ++k) acc = fmaf(wrow[k], X[k * D + j], acc);
  R[i * D + j] = (i == j ? 2.0f : 0.0f) - acc;
}

__global__ __launch_bounds__(256) void nr_mult_bf16(const float* __restrict__ X,
                                                    const float* __restrict__ R,
                                                    u16* __restrict__ Yb) {
  __shared__ float xrow[D];
  const int i = blockIdx.x, j = threadIdx.x;
  xrow[j] = X[i * D + j];
  __syncthreads();
  float acc = 0.f;
#pragma unroll 8
  for (int k = 0; k < D; ++k) acc = fmaf(xrow[k], R[k * D + j], acc);
  Yb[i * D + j] = f2bf(acc);
}

__global__ __launch_bounds__(256) void wconv(const float* __restrict__ W,
                                             u16* __restrict__ Wb) {
  const int i = blockIdx.x * 256 + threadIdx.x;
  Wb[i] = f2bf(W[i]);
}

// ---------------------------------------------------------------------------
// dist v2 (proven): 256 thr, A-fragments in registers (wave = 32 rows x 128
// cols), B double-buffered in LDS (2x32KB) -> 2 blocks/CU.
// ---------------------------------------------------------------------------
__global__ __launch_bounds__(256, 2) void dist_kernel(
    const float* __restrict__ p1, const float* __restrict__ p2,
    const u16* __restrict__ Qb, const u16* __restrict__ Fb,
    const float* __restrict__ n1, const float* __restrict__ n2,
    const float* __restrict__ nqp0, const float* __restrict__ nqp1,
    const float* __restrict__ nfp0, const float* __restrict__ nfp1,
    float* __restrict__ partial) {
  extern __shared__ char smem[];
  const int bid = blockIdx.x;
  const int lb = (bid & 7) * 128 + (bid >> 3);   // XCD-chunked swizzle
  const int c = lb >> 4, dir = (lb >> 3) & 1, it = lb & 7;
  const float* Ain = dir ? p2 : p1;
  const u16* Bin = dir ? Fb : Qb;
  const float* nA = dir ? n2 : n1;
  const float* nB0 = dir ? nfp0 : nqp0;
  const float* nB1 = dir ? nfp1 : nqp1;
  const int tx = threadIdx.x, wid = tx >> 6, l = tx & 63;
  const int l4 = l >> 4, lm = l & 15;

  auto issue_b = [&](int half, int jt) {
    const size_t base = ((size_t)(c << 10) + jt * 128) * D;
#pragma unroll
    for (int jf = 0; jf < 8; ++jf) {
      const u16* src = Bin + base + (size_t)(jf * 16 + lm) * D
                       + half * 128 + wid * 32 + l4 * 8;
      gload_lds16(src, smem + half * 32768 + (wid * 8 + jf) * 1024);
    }
  };

  issue_b(0, 0);
  bfv8 afr[2][8];
  const float* abase = Ain + ((size_t)(it * 128 + wid * 32) * NC + c) * D;
#pragma unroll
  for (int m = 0; m < 2; ++m)
#pragma unroll
    for (int ks = 0; ks < 8; ++ks) {
      const float* ap = abase + (size_t)(m * 16 + lm) * (NC * D) + ks * 32 + l4 * 8;
      float4 v0 = *(const float4*)(ap);
      float4 v1 = *(const float4*)(ap + 4);
      union { bfv8 v; uint4 u; } cv;
      cv.u.x = pk2(v0.x, v0.y); cv.u.y = pk2(v0.z, v0.w);
      cv.u.z = pk2(v1.x, v1.y); cv.u.w = pk2(v1.z, v1.w);
      afr[m][ks] = cv.v;
    }
  float na[2][4];
#pragma unroll
  for (int m = 0; m < 2; ++m)
#pragma unroll
    for (int rr = 0; rr < 4; ++rr)
      na[m][rr] = nA[(c << 10) + it * 128 + wid * 32 + m * 16 + l4 * 4 + rr];
  float minv[2][4];
#pragma unroll
  for (int m = 0; m < 2; ++m)
#pragma unroll
    for (int rr = 0; rr < 4; ++rr) minv[m][rr] = 3.0e38f;
  __syncthreads();

  const bfv8* lds8 = (const bfv8*)smem;
  for (int jt = 0; jt < 8; ++jt) {
    f32x4 acc[2][8];
#pragma unroll
    for (int m = 0; m < 2; ++m)
#pragma unroll
      for (int n = 0; n < 8; ++n) acc[m][n] = f32x4{0.f, 0.f, 0.f, 0.f};
    float nbv[8];
#pragma unroll
    for (int n = 0; n < 8; ++n) {
      const int idx = (c << 10) + jt * 128 + n * 16 + lm;
      nbv[n] = nB0[idx] + nB1[idx];
    }
    issue_b(1, jt);
#pragma unroll
    for (int ks = 0; ks < 4; ++ks) {
      bfv8 bb[8];
#pragma unroll
      for (int n = 0; n < 8; ++n) bb[n] = lds8[(ks * 8 + n) * 64 + l];
#pragma unroll
      for (int m = 0; m < 2; ++m)
#pragma unroll
        for (int n = 0; n < 8; ++n)
          acc[m][n] = __builtin_amdgcn_mfma_f32_16x16x32_bf16(afr[m][ks], bb[n], acc[m][n], 0, 0, 0);
    }
    __syncthreads();
    if (jt < 7) issue_b(0, jt + 1);
#pragma unroll
    for (int ks = 4; ks < 8; ++ks) {
      bfv8 bb[8];
#pragma unroll
      for (int n = 0; n < 8; ++n) bb[n] = lds8[2048 + ((ks - 4) * 8 + n) * 64 + l];
#pragma unroll
      for (int m = 0; m < 2; ++m)
#pragma unroll
        for (int n = 0; n < 8; ++n)
          acc[m][n] = __builtin_amdgcn_mfma_f32_16x16x32_bf16(afr[m][ks], bb[n], acc[m][n], 0, 0, 0);
    }
#pragma unroll
    for (int m = 0; m < 2; ++m)
#pragma unroll
      for (int n = 0; n < 8; ++n)
#pragma unroll
        for (int rr = 0; rr < 4; ++rr) {
          const float dd = na[m][rr] + nbv[n] - 2.0f * acc[m][n][rr];
          minv[m][rr] = fminf(minv[m][rr], dd);
        }
    __syncthreads();
  }
  float* red = (float*)(smem + 65536);
#pragma unroll
  for (int m = 0; m < 2; ++m)
#pragma unroll
    for (int rr = 0; rr < 4; ++rr) {
      float mm = minv[m][rr];
      mm = fminf(mm, __shfl_xor(mm, 1, 64));
      mm = fminf(mm, __shfl_xor(mm, 2, 64));
      mm = fminf(mm, __shfl_xor(mm, 4, 64));
      mm = fminf(mm, __shfl_xor(mm, 8, 64));
      if (lm == 0) red[wid * 32 + m * 16 + l4 * 4 + rr] = mm;
    }
  __syncthreads();
  if (tx < 128) {
    float v = red[tx];
#pragma unroll
    for (int off = 32; off; off >>= 1) v += __shfl_xor(v, off, 64);
    if ((tx & 63) == 0) red[128 + (tx >> 6)] = v;
  }
  __syncthreads();
  if (tx == 0) partial[lb] = red[128] + red[129];
}

__global__ void finalize_kernel(const float* __restrict__ partial,
                                float* __restrict__ out) {
  const int tx = threadIdx.x;
  if (tx >= 128) return;
  const int dir = tx >> 6, c = tx & 63;
  float s = 0.f;
#pragma unroll
  for (int it = 0; it < 8; ++it) s += partial[(c << 4) | (dir << 3) | it];
  out[dir * 64 + c] = s * (1.0f / 1024.0f);
}

extern "C" void kernel_launch(void* const* d_in, const int* in_sizes, int n_in,
                              void* d_out, int out_size, void* d_ws, size_t ws_size,
                              hipStream_t stream) {
  const float* p1 = (const float*)d_in[0];
  const float* p2 = (const float*)d_in[1];
  const float* W  = (const float*)d_in[2];
  const float* bv = (const float*)d_in[3];
  float* out = (float*)d_out;
  char* ws = (char*)d_ws;
  float* n1   = (float*)(ws);                    // 256KB
  float* n2   = (float*)(ws + (256 << 10));      // 256KB
  float* nfp0 = (float*)(ws + (512 << 10));      // 256KB
  float* nfp1 = (float*)(ws + (768 << 10));      // 256KB
  float* nqp0 = (float*)(ws + (1024 << 10));     // 256KB
  float* nqp1 = (float*)(ws + (1280 << 10));     // 256KB
  float* partial = (float*)(ws + (1536 << 10));  // 4KB
  u16* Wb  = (u16*)(ws + (1544 << 10));          // 128KB
  u16* IWb = (u16*)(ws + (1672 << 10));          // 128KB
  float* IWa = (float*)(ws + (1800 << 10));      // 256KB
  float* Rt  = (float*)(ws + (2056 << 10));      // 256KB
  u16* Fb  = (u16*)(ws + (2560 << 10));                   // 32MB
  u16* Qb  = (u16*)(ws + (2560 << 10) + (32u << 20));     // 32MB

  hipFuncSetAttribute((const void*)phase1_kernel,
                      hipFuncAttributeMaxDynamicSharedMemorySize, PH_LDS);
  hipFuncSetAttribute((const void*)phase3_kernel,
                      hipFuncAttributeMaxDynamicSharedMemorySize, PH_LDS);
  hipFuncSetAttribute((const void*)dist_kernel,
                      hipFuncAttributeMaxDynamicSharedMemorySize, DIST_LDS);

  wconv<<<256, 256, 0, stream>>>(W, Wb);
  // gj (block 0, MFMA update) runs concurrently with F-prep + n2 norms
  phase1_kernel<<<1089, 512, PH_LDS, stream>>>(p1, p2, W, Wb, bv, Fb,
                                               n1, n2, nfp0, nfp1, IWa);
  // one Newton-Schulz refinement (fp32), bf16 output
  nr_residual<<<256, 256, 0, stream>>>(W, IWa, Rt);
  nr_mult_bf16<<<256, 256, 0, stream>>>(IWa, Rt, IWb);
  phase3_kernel<<<1024, 512, PH_LDS, stream>>>(p2, IWb, bv, Qb, nqp0, nqp1);
  dist_kernel<<<1024, 256, DIST_LDS, stream>>>(p1, p2, Qb, Fb, n1, n2,
                                               nqp0, nqp1, nfp0, nfp1, partial);
  finalize_kernel<<<1, 128, 0, stream>>>(partial, out);
}

// Round 7
// 298.122 us; speedup vs baseline: 1.9473x; 1.1387x over previous
//
#include <hip/hip_runtime.h>

#define D 256
#define NC 64

using u16 = unsigned short;
using u32 = unsigned int;

typedef __attribute__((ext_vector_type(8))) short bfv8;   // 8 bf16 = 16 B
typedef __attribute__((ext_vector_type(4))) float f32x4;

__device__ __forceinline__ float bf2f(u32 u) {
  union { u32 i; float f; } v; v.i = u << 16; return v.f;
}
__device__ __forceinline__ u16 f2bf(float f) {
  union { float f; u32 i; } v; v.f = f;
  u32 x = v.i;
  return (u16)((x + 0x7FFFu + ((x >> 16) & 1u)) >> 16);  // RTNE
}
__device__ __forceinline__ u32 pk2(float a, float b) {
  return (u32)f2bf(a) | ((u32)f2bf(b) << 16);
}
__device__ __forceinline__ size_t cmrow(int g) {   // class-major row index
  return (size_t)(((g & 63) << 10) | (g >> 6));
}

__device__ __forceinline__ void gload_lds16(const void* src, void* dst) {
  __builtin_amdgcn_global_load_lds(
      (const __attribute__((address_space(1))) void*)src,
      (__attribute__((address_space(3))) void*)dst, 16, 0, 0);
}

#define PH_LDS 70912    // gj: Ml 20480 + Arow 16384 + G 16384 + Gfrag 16384 + Pinv 1280
#define DIST_LDS 66560  // B dbuf 2x32K + red

// ---------------------------------------------------------------------------
// Blocked Gauss-Jordan inverse, NB=16, 1024 threads (16 waves), MFMA update.
// Wave w owns rows 16w..16w+15 in MFMA C-fragment layout: f32x4 x[ct],
// element (i,j) of 16x16 tile ct: lane = j + 16*(i>>2), reg = i&3.
// State = 64 VGPRs/thread -> no spill (round-6's 8-wave version spilled).
// Update x += (-M)*G via 2 MFMAs/tile with bf16 hi/lo split.
// ---------------------------------------------------------------------------
__device__ void gj_body(const float* __restrict__ W, float* __restrict__ IW,
                        char* smem) {
  float (*Ml)[20]    = (float(*)[20])smem;                 // 20480 B
  float (*Arow)[256] = (float(*)[256])(smem + 20480);      // 16384 B
  float (*G)[256]    = (float(*)[256])(smem + 36864);      // 16384 B
  u16*  Gfrag        = (u16*)(smem + 53248);               // 16384 B
  float (*Pinv)[20]  = (float(*)[20])(smem + 69632);       // 1280 B
  const int t = threadIdx.x, w = t >> 6, l = t & 63;
  const int lj = l & 15, lh = l >> 4;
  const int r0 = 16 * w;

  f32x4 x[16];
#pragma unroll
  for (int ct = 0; ct < 16; ++ct)
#pragma unroll
    for (int reg = 0; reg < 4; ++reg)
      x[ct][reg] = W[(size_t)(r0 + 4 * lh + reg) * D + 16 * ct + lj];

  for (int s = 0; s < 16; ++s) {
    // -------- Phase A: stage panel col-tile; pivot wave stages its rows ----
#pragma unroll
    for (int ct = 0; ct < 16; ++ct)
      if (ct == s)
#pragma unroll
        for (int reg = 0; reg < 4; ++reg)
          Ml[r0 + 4 * lh + reg][lj] = x[ct][reg];
    if (w == s) {
#pragma unroll
      for (int ct = 0; ct < 16; ++ct)
#pragma unroll
        for (int reg = 0; reg < 4; ++reg)
          Arow[4 * lh + reg][16 * ct + lj] = x[ct][reg];
    }
    __syncthreads();
    // -------- Phase B: serial 16x16 pivot-block inverse (proven) -----------
    if (t < 16) {
      float p[16];
      {
        float4 rr0 = *(const float4*)&Ml[16 * s + t][0];
        float4 rr1 = *(const float4*)&Ml[16 * s + t][4];
        float4 rr2 = *(const float4*)&Ml[16 * s + t][8];
        float4 rr3 = *(const float4*)&Ml[16 * s + t][12];
        p[0] = rr0.x; p[1] = rr0.y; p[2] = rr0.z; p[3] = rr0.w;
        p[4] = rr1.x; p[5] = rr1.y; p[6] = rr1.z; p[7] = rr1.w;
        p[8] = rr2.x; p[9] = rr2.y; p[10] = rr2.z; p[11] = rr2.w;
        p[12] = rr3.x; p[13] = rr3.y; p[14] = rr3.z; p[15] = rr3.w;
      }
#pragma unroll
      for (int pp = 0; pp < 16; ++pp) {
        float u[16];
#pragma unroll
        for (int j = 0; j < 16; ++j)
          u[j] = __int_as_float(__builtin_amdgcn_readlane(__float_as_int(p[j]), pp));
        const float pv = u[pp];
        const float d = 1.0f / pv;
        if (t == pp) {
#pragma unroll
          for (int j = 0; j < 16; ++j) p[j] = u[j] * d;
          p[pp] = d;
        } else {
          const float md = p[pp] * d;
          u[pp] = pv + 1.0f;
#pragma unroll
          for (int j = 0; j < 16; ++j) p[j] = fmaf(-md, u[j], p[j]);
        }
      }
#pragma unroll
      for (int j = 0; j < 16; ++j) Pinv[t][j] = p[j];
    }
    __syncthreads();
    // -------- Phase C: G row w = Pinv[w]*Arow + bf16 frag-ordered copy -----
    {
      const bool inC = ((l >> 2) == s);
      const int co = (l & 3) << 2;
      const int gct = l >> 2;
      const int kk = w;
      float4 g = make_float4(0.f, 0.f, 0.f, 0.f);
#pragma unroll
      for (int q = 0; q < 16; ++q) {
        const float pv = Pinv[kk][q];
        const float4 av = *(const float4*)&Arow[q][4 * l];
        g.x = fmaf(pv, av.x, g.x); g.y = fmaf(pv, av.y, g.y);
        g.z = fmaf(pv, av.z, g.z); g.w = fmaf(pv, av.w, g.w);
      }
      if (inC) {
        g.x = Pinv[kk][co + 0] + (kk == co + 0 ? 1.f : 0.f);
        g.y = Pinv[kk][co + 1] + (kk == co + 1 ? 1.f : 0.f);
        g.z = Pinv[kk][co + 2] + (kk == co + 2 ? 1.f : 0.f);
        g.w = Pinv[kk][co + 3] + (kk == co + 3 ? 1.f : 0.f);
      }
      *(float4*)&G[kk][4 * l] = g;
      const int e0 = kk & 7;
      const int lbase = 16 * (kk >> 3);
      const float gv[4] = {g.x, g.y, g.z, g.w};
#pragma unroll
      for (int cc = 0; cc < 4; ++cc) {
        const int cl = 4 * (l & 3) + cc;
        const u16 hi = f2bf(gv[cc]);
        const u16 lo = f2bf(gv[cc] - bf2f(hi));
        Gfrag[(gct * 64 + lbase + cl) * 8 + e0] = hi;
        Gfrag[(gct * 64 + 32 + lbase + cl) * 8 + e0] = lo;
      }
    }
    __syncthreads();
    // -------- Phase D: MFMA update / pivot-tile readback --------------------
    bfv8 afr;
    {
      const int row = r0 + lj;
      float4 f0 = *(const float4*)&Ml[row][8 * (lh & 1)];
      float4 f1 = *(const float4*)&Ml[row][8 * (lh & 1) + 4];
      const float fv[8] = {f0.x, f0.y, f0.z, f0.w, f1.x, f1.y, f1.z, f1.w};
      union { bfv8 v; u16 e[8]; } A;
      if (lh < 2) {
#pragma unroll
        for (int e = 0; e < 8; ++e) A.e[e] = f2bf(-fv[e]);
      } else {
#pragma unroll
        for (int e = 0; e < 8; ++e) {
          const float hi = bf2f(f2bf(fv[e]));
          A.e[e] = f2bf(-(fv[e] - hi));
        }
      }
      afr = A.v;
    }
    if (w != s) {
#pragma unroll
      for (int ct = 0; ct < 16; ++ct) {
        bfv8 b1 = *(const bfv8*)&Gfrag[(ct * 64 + l) * 8];
        bfv8 b2 = *(const bfv8*)&Gfrag[(ct * 64 + (l ^ 32)) * 8];
        x[ct] = __builtin_amdgcn_mfma_f32_16x16x32_bf16(afr, b1, x[ct], 0, 0, 0);
        x[ct] = __builtin_amdgcn_mfma_f32_16x16x32_bf16(afr, b2, x[ct], 0, 0, 0);
      }
    } else {
#pragma unroll
      for (int ct = 0; ct < 16; ++ct) {
        if (ct == s) {
#pragma unroll
          for (int reg = 0; reg < 4; ++reg)
            x[ct][reg] = Pinv[4 * lh + reg][lj];
        } else {
#pragma unroll
          for (int reg = 0; reg < 4; ++reg)
            x[ct][reg] = G[4 * lh + reg][16 * ct + lj];
        }
      }
    }
    __syncthreads();
  }
#pragma unroll
  for (int ct = 0; ct < 16; ++ct)
#pragma unroll
    for (int reg = 0; reg < 4; ++reg)
      IW[(size_t)(r0 + 4 * lh + reg) * D + 16 * ct + lj] = x[ct][reg];
}

// ---------------------------------------------------------------------------
// prep body, 1024 threads: block = 128 rows x FULL 256 cols x K256.
// B fragments in registers, A staged in LDS (round-4-proven staging).
// Out = bf16(A)@Brows^T + bias, class-major. Fused exact input norms
// (WRITE_NRM) + complete rounded-output row norms (nfp, no split).
// Waves: 16 = 2 (mw: 64 rows) x 8 (nw: 32 cols).
// ---------------------------------------------------------------------------
template <int MODE, bool WRITE_NRM>
__device__ void prep_body(const float* __restrict__ Ain,
                          const u16* __restrict__ Brows,
                          const float* __restrict__ biasv,
                          u16* __restrict__ Out, float* __restrict__ nrm,
                          float* __restrict__ nfp, int it, char* smem) {
  const int tx = threadIdx.x, ww = tx >> 6, l = tx & 63;
  const int mw = ww >> 3, nw = ww & 7, l4 = l >> 4, lm = l & 15;
  char* Ab = smem;
  float* nfpart = (float*)(smem + 65536);  // [8][128]

  bfv8 bfr[2][8];
#pragma unroll
  for (int nf2 = 0; nf2 < 2; ++nf2)
#pragma unroll
    for (int ks = 0; ks < 8; ++ks)
      bfr[nf2][ks] = *(const bfv8*)(Brows +
          (size_t)(nw * 32 + nf2 * 16 + lm) * D + ks * 32 + l4 * 8);

  {
    const int r = tx >> 3, sg = tx & 7;
    const float* arow = Ain + (size_t)(it * 128 + r) * D + sg * 32;
    float ss = 0.f;
#pragma unroll
    for (int g2 = 0; g2 < 4; ++g2) {
      float4 v0 = *(const float4*)(arow + g2 * 8);
      float4 v1 = *(const float4*)(arow + g2 * 8 + 4);
      ss = fmaf(v0.x, v0.x, fmaf(v0.y, v0.y, fmaf(v0.z, v0.z, fmaf(v0.w, v0.w, ss))));
      ss = fmaf(v1.x, v1.x, fmaf(v1.y, v1.y, fmaf(v1.z, v1.z, fmaf(v1.w, v1.w, ss))));
      uint4 w4;
      w4.x = pk2(v0.x, v0.y); w4.y = pk2(v0.z, v0.w);
      w4.z = pk2(v1.x, v1.y); w4.w = pk2(v1.z, v1.w);
      *(uint4*)(Ab + (sg * 8 + (r >> 4)) * 1024 + ((r & 15) + g2 * 16) * 16) = w4;
    }
    ss += __shfl_xor(ss, 1, 64);
    ss += __shfl_xor(ss, 2, 64);
    ss += __shfl_xor(ss, 4, 64);
    if (WRITE_NRM && sg == 0) nrm[cmrow(it * 128 + r)] = ss;
  }
  __syncthreads();

  const bfv8* A8 = (const bfv8*)Ab;
  f32x4 acc[4][2];
#pragma unroll
  for (int mf = 0; mf < 4; ++mf) {
    acc[mf][0] = f32x4{0.f, 0.f, 0.f, 0.f};
    acc[mf][1] = f32x4{0.f, 0.f, 0.f, 0.f};
  }
#pragma unroll
  for (int ks = 0; ks < 8; ++ks)
#pragma unroll
    for (int mf = 0; mf < 4; ++mf) {
      bfv8 a = A8[(ks * 8 + mw * 4 + mf) * 64 + l];
      acc[mf][0] = __builtin_amdgcn_mfma_f32_16x16x32_bf16(a, bfr[0][ks], acc[mf][0], 0, 0, 0);
      acc[mf][1] = __builtin_amdgcn_mfma_f32_16x16x32_bf16(a, bfr[1][ks], acc[mf][1], 0, 0, 0);
    }

  float bias[2];
  if (MODE == 0) {
#pragma unroll
    for (int nf2 = 0; nf2 < 2; ++nf2)
      bias[nf2] = biasv[nw * 32 + nf2 * 16 + lm];
  } else {
#pragma unroll
    for (int nf2 = 0; nf2 < 2; ++nf2) {
      float pd = 0.f;
#pragma unroll
      for (int ks = 0; ks < 8; ++ks) {
        float4 b0 = *(const float4*)(biasv + ks * 32 + l4 * 8);
        float4 b1 = *(const float4*)(biasv + ks * 32 + l4 * 8 + 4);
        pd = fmaf(b0.x, bf2f((u16)bfr[nf2][ks][0]), pd);
        pd = fmaf(b0.y, bf2f((u16)bfr[nf2][ks][1]), pd);
        pd = fmaf(b0.z, bf2f((u16)bfr[nf2][ks][2]), pd);
        pd = fmaf(b0.w, bf2f((u16)bfr[nf2][ks][3]), pd);
        pd = fmaf(b1.x, bf2f((u16)bfr[nf2][ks][4]), pd);
        pd = fmaf(b1.y, bf2f((u16)bfr[nf2][ks][5]), pd);
        pd = fmaf(b1.z, bf2f((u16)bfr[nf2][ks][6]), pd);
        pd = fmaf(b1.w, bf2f((u16)bfr[nf2][ks][7]), pd);
      }
      pd += __shfl_xor(pd, 16, 64);
      pd += __shfl_xor(pd, 32, 64);
      bias[nf2] = -pd;
    }
  }

#pragma unroll
  for (int mf = 0; mf < 4; ++mf)
#pragma unroll
    for (int rr = 0; rr < 4; ++rr) {
      const int g = it * 128 + mw * 64 + mf * 16 + l4 * 4 + rr;
      const size_t orow = cmrow(g) * D;
      float v2 = 0.f;
#pragma unroll
      for (int nf2 = 0; nf2 < 2; ++nf2) {
        const float v = acc[mf][nf2][rr] + bias[nf2];
        const u16 hv = f2bf(v);
        Out[orow + nw * 32 + nf2 * 16 + lm] = hv;
        const float vr = bf2f(hv);
        v2 = fmaf(vr, vr, v2);
      }
      v2 += __shfl_xor(v2, 1, 64);
      v2 += __shfl_xor(v2, 2, 64);
      v2 += __shfl_xor(v2, 4, 64);
      v2 += __shfl_xor(v2, 8, 64);
      if (lm == 0) nfpart[nw * 128 + mw * 64 + mf * 16 + l4 * 4 + rr] = v2;
    }
  __syncthreads();
  if (tx < 128) {
    float s = 0.f;
#pragma unroll
    for (int q = 0; q < 8; ++q) s += nfpart[q * 128 + tx];
    nfp[cmrow(it * 128 + tx)] = s;
  }
}

// n2 norms role: 32 blocks x 1024 thr, 2048 rows each, class-major write
__device__ void norms_role(const float* __restrict__ p2, float* __restrict__ n2,
                           int idx) {
  const int tx = threadIdx.x, q = tx & 3;
#pragma unroll
  for (int rep = 0; rep < 8; ++rep) {
    const int g = idx * 2048 + rep * 256 + (tx >> 2);
    const float* row = p2 + (size_t)g * D + q * 64;
    float ss = 0.f;
#pragma unroll
    for (int g2 = 0; g2 < 16; ++g2) {
      float4 v = *(const float4*)(row + g2 * 4);
      ss = fmaf(v.x, v.x, fmaf(v.y, v.y, fmaf(v.z, v.z, fmaf(v.w, v.w, ss))));
    }
    ss += __shfl_xor(ss, 1, 64);
    ss += __shfl_xor(ss, 2, 64);
    if (q == 0) n2[cmrow(g)] = ss;
  }
}

// phase1: block 0 = gj inverse; 1..512 = prep<0> (F); 513..544 = n2 norms
__global__ __launch_bounds__(1024, 1) void phase1_kernel(
    const float* __restrict__ p1, const float* __restrict__ p2,
    const float* __restrict__ W, const u16* __restrict__ Wb,
    const float* __restrict__ bv, u16* __restrict__ Fb,
    float* __restrict__ n1, float* __restrict__ n2,
    float* __restrict__ nf, float* __restrict__ IWa) {
  extern __shared__ char smem[];
  const int b = blockIdx.x;
  if (b == 0) {
    gj_body(W, IWa, smem);
  } else if (b <= 512) {
    prep_body<0, true>(p1, Wb, bv, Fb, n1, nf, b - 1, smem);
  } else {
    norms_role(p2, n2, b - 513);
  }
}

// phase3: prep<1> (Q = (p2-b)@IW^T via bias fold)
__global__ __launch_bounds__(1024, 1) void phase3_kernel(
    const float* __restrict__ p2, const u16* __restrict__ IWb,
    const float* __restrict__ bv, u16* __restrict__ Qb,
    float* __restrict__ nq) {
  extern __shared__ char smem[];
  prep_body<1, false>(p2, IWb, bv, Qb, nullptr, nq, blockIdx.x, smem);
}

// ---------------------------------------------------------------------------
// Newton-Schulz (one iteration): R = 2I - W*X ; Y = X*R -> bf16
// ---------------------------------------------------------------------------
__global__ __launch_bounds__(256) void nr_residual(const float* __restrict__ W,
                                                   const float* __restrict__ X,
                                                   float* __restrict__ R) {
  __shared__ float wrow[D];
  const int i = blockIdx.x, j = threadIdx.x;
  wrow[j] = W[i * D + j];
  __syncthreads();
  float acc = 0.f;
#pragma unroll 8
  for (int k = 0; k < D; ++k) acc = fmaf(wrow[k], X[k * D + j], acc);
  R[i * D + j] = (i == j ? 2.0f : 0.0f) - acc;
}

__global__ __launch_bounds__(256) void nr_mult_bf16(const float* __restrict__ X,
                                                    const float* __restrict__ R,
                                                    u16* __restrict__ Yb) {
  __shared__ float xrow[D];
  const int i = blockIdx.x, j = threadIdx.x;
  xrow[j] = X[i * D + j];
  __syncthreads();
  float acc = 0.f;
#pragma unroll 8
  for (int k = 0; k < D; ++k) acc = fmaf(xrow[k], R[k * D + j], acc);
  Yb[i * D + j] = f2bf(acc);
}

__global__ __launch_bounds__(256) void wconv(const float* __restrict__ W,
                                             u16* __restrict__ Wb) {
  const int i = blockIdx.x * 256 + threadIdx.x;
  Wb[i] = f2bf(W[i]);
}

// ---------------------------------------------------------------------------
// dist (proven): 256 thr, A-fragments in registers (wave = 32 rows x 128
// cols), B double-buffered in LDS (2x32KB) -> 2 blocks/CU.
// ---------------------------------------------------------------------------
__global__ __launch_bounds__(256, 2) void dist_kernel(
    const float* __restrict__ p1, const float* __restrict__ p2,
    const u16* __restrict__ Qb, const u16* __restrict__ Fb,
    const float* __restrict__ n1, const float* __restrict__ n2,
    const float* __restrict__ nq, const float* __restrict__ nf,
    float* __restrict__ partial) {
  extern __shared__ char smem[];
  const int bid = blockIdx.x;
  const int lb = (bid & 7) * 128 + (bid >> 3);   // XCD-chunked swizzle
  const int c = lb >> 4, dir = (lb >> 3) & 1, it = lb & 7;
  const float* Ain = dir ? p2 : p1;
  const u16* Bin = dir ? Fb : Qb;
  const float* nA = dir ? n2 : n1;
  const float* nB = dir ? nf : nq;
  const int tx = threadIdx.x, wid = tx >> 6, l = tx & 63;
  const int l4 = l >> 4, lm = l & 15;

  auto issue_b = [&](int half, int jt) {
    const size_t base = ((size_t)(c << 10) + jt * 128) * D;
#pragma unroll
    for (int jf = 0; jf < 8; ++jf) {
      const u16* src = Bin + base + (size_t)(jf * 16 + lm) * D
                       + half * 128 + wid * 32 + l4 * 8;
      gload_lds16(src, smem + half * 32768 + (wid * 8 + jf) * 1024);
    }
  };

  issue_b(0, 0);
  bfv8 afr[2][8];
  const float* abase = Ain + ((size_t)(it * 128 + wid * 32) * NC + c) * D;
#pragma unroll
  for (int m = 0; m < 2; ++m)
#pragma unroll
    for (int ks = 0; ks < 8; ++ks) {
      const float* ap = abase + (size_t)(m * 16 + lm) * (NC * D) + ks * 32 + l4 * 8;
      float4 v0 = *(const float4*)(ap);
      float4 v1 = *(const float4*)(ap + 4);
      union { bfv8 v; uint4 u; } cv;
      cv.u.x = pk2(v0.x, v0.y); cv.u.y = pk2(v0.z, v0.w);
      cv.u.z = pk2(v1.x, v1.y); cv.u.w = pk2(v1.z, v1.w);
      afr[m][ks] = cv.v;
    }
  float na[2][4];
#pragma unroll
  for (int m = 0; m < 2; ++m)
#pragma unroll
    for (int rr = 0; rr < 4; ++rr)
      na[m][rr] = nA[(c << 10) + it * 128 + wid * 32 + m * 16 + l4 * 4 + rr];
  float minv[2][4];
#pragma unroll
  for (int m = 0; m < 2; ++m)
#pragma unroll
    for (int rr = 0; rr < 4; ++rr) minv[m][rr] = 3.0e38f;
  __syncthreads();

  const bfv8* lds8 = (const bfv8*)smem;
  for (int jt = 0; jt < 8; ++jt) {
    f32x4 acc[2][8];
#pragma unroll
    for (int m = 0; m < 2; ++m)
#pragma unroll
      for (int n = 0; n < 8; ++n) acc[m][n] = f32x4{0.f, 0.f, 0.f, 0.f};
    float nbv[8];
#pragma unroll
    for (int n = 0; n < 8; ++n)
      nbv[n] = nB[(c << 10) + jt * 128 + n * 16 + lm];
    issue_b(1, jt);
#pragma unroll
    for (int ks = 0; ks < 4; ++ks) {
      bfv8 bb[8];
#pragma unroll
      for (int n = 0; n < 8; ++n) bb[n] = lds8[(ks * 8 + n) * 64 + l];
#pragma unroll
      for (int m = 0; m < 2; ++m)
#pragma unroll
        for (int n = 0; n < 8; ++n)
          acc[m][n] = __builtin_amdgcn_mfma_f32_16x16x32_bf16(afr[m][ks], bb[n], acc[m][n], 0, 0, 0);
    }
    __syncthreads();
    if (jt < 7) issue_b(0, jt + 1);
#pragma unroll
    for (int ks = 4; ks < 8; ++ks) {
      bfv8 bb[8];
#pragma unroll
      for (int n = 0; n < 8; ++n) bb[n] = lds8[2048 + ((ks - 4) * 8 + n) * 64 + l];
#pragma unroll
      for (int m = 0; m < 2; ++m)
#pragma unroll
        for (int n = 0; n < 8; ++n)
          acc[m][n] = __builtin_amdgcn_mfma_f32_16x16x32_bf16(afr[m][ks], bb[n], acc[m][n], 0, 0, 0);
    }
#pragma unroll
    for (int m = 0; m < 2; ++m)
#pragma unroll
      for (int n = 0; n < 8; ++n)
#pragma unroll
        for (int rr = 0; rr < 4; ++rr) {
          const float dd = na[m][rr] + nbv[n] - 2.0f * acc[m][n][rr];
          minv[m][rr] = fminf(minv[m][rr], dd);
        }
    __syncthreads();
  }
  float* red = (float*)(smem + 65536);
#pragma unroll
  for (int m = 0; m < 2; ++m)
#pragma unroll
    for (int rr = 0; rr < 4; ++rr) {
      float mm = minv[m][rr];
      mm = fminf(mm, __shfl_xor(mm, 1, 64));
      mm = fminf(mm, __shfl_xor(mm, 2, 64));
      mm = fminf(mm, __shfl_xor(mm, 4, 64));
      mm = fminf(mm, __shfl_xor(mm, 8, 64));
      if (lm == 0) red[wid * 32 + m * 16 + l4 * 4 + rr] = mm;
    }
  __syncthreads();
  if (tx < 128) {
    float v = red[tx];
#pragma unroll
    for (int off = 32; off; off >>= 1) v += __shfl_xor(v, off, 64);
    if ((tx & 63) == 0) red[128 + (tx >> 6)] = v;
  }
  __syncthreads();
  if (tx == 0) partial[lb] = red[128] + red[129];
}

__global__ void finalize_kernel(const float* __restrict__ partial,
                                float* __restrict__ out) {
  const int tx = threadIdx.x;
  if (tx >= 128) return;
  const int dir = tx >> 6, c = tx & 63;
  float s = 0.f;
#pragma unroll
  for (int it = 0; it < 8; ++it) s += partial[(c << 4) | (dir << 3) | it];
  out[dir * 64 + c] = s * (1.0f / 1024.0f);
}

extern "C" void kernel_launch(void* const* d_in, const int* in_sizes, int n_in,
                              void* d_out, int out_size, void* d_ws, size_t ws_size,
                              hipStream_t stream) {
  const float* p1 = (const float*)d_in[0];
  const float* p2 = (const float*)d_in[1];
  const float* W  = (const float*)d_in[2];
  const float* bv = (const float*)d_in[3];
  float* out = (float*)d_out;
  char* ws = (char*)d_ws;
  float* n1   = (float*)(ws);                    // 256KB
  float* n2   = (float*)(ws + (256 << 10));      // 256KB
  float* nf   = (float*)(ws + (512 << 10));      // 256KB
  float* nq   = (float*)(ws + (768 << 10));      // 256KB
  float* partial = (float*)(ws + (1024 << 10));  // 4KB
  u16* Wb  = (u16*)(ws + (1032 << 10));          // 128KB
  u16* IWb = (u16*)(ws + (1160 << 10));          // 128KB
  float* IWa = (float*)(ws + (1288 << 10));      // 256KB
  float* Rt  = (float*)(ws + (1544 << 10));      // 256KB
  u16* Fb  = (u16*)(ws + (2048 << 10));                   // 32MB
  u16* Qb  = (u16*)(ws + (2048 << 10) + (32u << 20));     // 32MB

  hipFuncSetAttribute((const void*)phase1_kernel,
                      hipFuncAttributeMaxDynamicSharedMemorySize, PH_LDS);
  hipFuncSetAttribute((const void*)phase3_kernel,
                      hipFuncAttributeMaxDynamicSharedMemorySize, PH_LDS);
  hipFuncSetAttribute((const void*)dist_kernel,
                      hipFuncAttributeMaxDynamicSharedMemorySize, DIST_LDS);

  wconv<<<256, 256, 0, stream>>>(W, Wb);
  // gj (block 0, 16-wave MFMA, no spill) || F-prep (512 blocks) || n2 norms
  phase1_kernel<<<545, 1024, PH_LDS, stream>>>(p1, p2, W, Wb, bv, Fb,
                                               n1, n2, nf, IWa);
  // one Newton-Schulz refinement (fp32), bf16 output
  nr_residual<<<256, 256, 0, stream>>>(W, IWa, Rt);
  nr_mult_bf16<<<256, 256, 0, stream>>>(IWa, Rt, IWb);
  phase3_kernel<<<512, 1024, PH_LDS, stream>>>(p2, IWb, bv, Qb, nq);
  dist_kernel<<<1024, 256, DIST_LDS, stream>>>(p1, p2, Qb, Fb, n1, n2,
                                               nq, nf, partial);
  finalize_kernel<<<1, 128, 0, stream>>>(partial, out);
}